// Round 5
// baseline (752.058 us; speedup 1.0000x reference)
//
#include <hip/hip_runtime.h>
#include <hip/hip_bf16.h>

#define DIN 256
#define DHID 128
#define NCLS 47
#define BCAP 4096          // per-bucket capacity (lambda ~2046, >40 sigma margin)

typedef __attribute__((ext_vector_type(8))) short short8;   // 8 bf16 (4 VGPRs)
typedef __attribute__((ext_vector_type(4))) float f32x4;

__device__ __forceinline__ short f2bf(float f) {
    __bf16 b = (__bf16)f;                 // RNE convert
    return __builtin_bit_cast(short, b);
}
__device__ __forceinline__ float bfu(unsigned int u) {   // low 16 bits = bf16
    return __uint_as_float(u << 16);
}

// ================= CSR build, pass A: bucket append ========================
// bucket = dst>>7; packed = src (17b) | (dst&127)<<17
__global__ void k_bucket(const int* __restrict__ src, const int* __restrict__ dst,
                         int* bcnt, unsigned int* __restrict__ bbuf, int E) {
    int e = blockIdx.x * blockDim.x + threadIdx.x;
    if (e < E) {
        int d = dst[e];
        int b = d >> 7;
        unsigned int p = (unsigned int)src[e] | ((unsigned int)(d & 127) << 17);
        int pos = atomicAdd(&bcnt[b], 1);
        if (pos < BCAP) bbuf[(size_t)b * BCAP + pos] = p;
    }
}

// ========= CSR build, pass B: per-bucket counting sort (in place) ==========
// one block (256 thr) per bucket; emits degi/beg/dinv coalesced; sorts src
// back into bbuf (aliased as ssrc).
__global__ __launch_bounds__(256) void k_bsort(int* __restrict__ bcnt,
                                               unsigned int* __restrict__ bbuf,
                                               int* __restrict__ degi,
                                               int* __restrict__ beg,
                                               float* __restrict__ dinv, int n) {
    __shared__ unsigned int stage[BCAP];
    __shared__ int hist[128];
    __shared__ int cur[128];
    __shared__ int wtot;

    int b = blockIdx.x, t = threadIdx.x;
    int cnt = min(bcnt[b], BCAP);
    size_t bbase = (size_t)b * BCAP;
    int node0 = b << 7;

    if (t < 128) hist[t] = 0;
    __syncthreads();

    // stage + histogram
    for (int i = t; i < cnt; i += 256) {
        unsigned int p = bbuf[bbase + i];
        stage[i] = p;
        atomicAdd(&hist[p >> 17], 1);
    }
    __syncthreads();

    // exclusive scan of 128 counters (2 waves)
    int v = 0, incl = 0;
    if (t < 128) {
        v = hist[t];
        incl = v;
        int lane = t & 63;
        #pragma unroll
        for (int off = 1; off < 64; off <<= 1) {
            int u = __shfl_up(incl, off, 64);
            if (lane >= off) incl += u;
        }
        if (t == 63) wtot = incl;
    }
    __syncthreads();
    if (t < 128) {
        int ex = incl - v + ((t >= 64) ? wtot : 0);
        cur[t] = ex;
        int node = node0 + t;
        if (node < n) {
            degi[node] = v;
            beg[node]  = (int)bbase + ex;
            dinv[node] = rsqrtf((float)(v + 1));   // +1 self-loop
        }
    }
    __syncthreads();

    // counting-sort scatter (LDS cursors), write src in place
    for (int i = t; i < cnt; i += 256) {
        unsigned int p = stage[i];
        int slot = atomicAdd(&cur[p >> 17], 1);
        bbuf[bbase + slot] = p & 0x1FFFFu;
    }
}

// ===================== W1 -> bf16 B-fragment swizzle =======================
__global__ void k_prepW1(const float* __restrict__ W1, short* __restrict__ W1s) {
    int tid = blockIdx.x * blockDim.x + threadIdx.x;   // 0..4095
    int frag = tid >> 6, lane = tid & 63;
    int kt = frag >> 3, nt = frag & 7;
    int quad = lane >> 4, col = lane & 15;
    #pragma unroll
    for (int j = 0; j < 8; ++j) {
        int k = kt * 32 + quad * 8 + j;
        W1s[(size_t)tid * 8 + j] = f2bf(W1[k * DHID + nt * 16 + col]);
    }
}

// ===================== W2 -> bf16 B-fragment swizzle (pad N to 64) =========
__global__ void k_prepW2(const float* __restrict__ W2, short* __restrict__ W2s) {
    int tid = blockIdx.x * blockDim.x + threadIdx.x;   // 0..1023
    int frag = tid >> 6, lane = tid & 63;
    int kt = frag >> 2, nt = frag & 3;
    int quad = lane >> 4, col = lane & 15;
    int c = nt * 16 + col;
    #pragma unroll
    for (int j = 0; j < 8; ++j) {
        int k = kt * 32 + quad * 8 + j;
        float v = (c < NCLS) ? W2[k * NCLS + c] : 0.0f;
        W2s[(size_t)tid * 8 + j] = f2bf(v);
    }
}

// ===================== GEMM1 via MFMA: hb = bf16(x @ W1) ===================
__global__ __launch_bounds__(256) void k_gemm1_mfma(const float* __restrict__ x,
                                                    const short* __restrict__ W1s,
                                                    short* __restrict__ hb, int n) {
    __shared__ short lw[32768];  // 64 KB: full swizzled W1
    {
        const uint4* g = (const uint4*)W1s;
        uint4* l = (uint4*)lw;
        for (int i = threadIdx.x; i < 4096; i += 256) l[i] = g[i];
    }
    __syncthreads();

    int wave = threadIdx.x >> 6, lane = threadIdx.x & 63;
    int quad = lane >> 4, lrow = lane & 15;
    long long rowbase = (long long)blockIdx.x * 128 + wave * 32;

    f32x4 acc[2][8];
    #pragma unroll
    for (int rt = 0; rt < 2; ++rt)
        #pragma unroll
        for (int nt = 0; nt < 8; ++nt) acc[rt][nt] = (f32x4){0.f, 0.f, 0.f, 0.f};

    const short8* lf = (const short8*)lw;

    #pragma unroll
    for (int kt = 0; kt < 8; ++kt) {
        int k0 = kt * 32 + quad * 8;
        short8 a[2];
        #pragma unroll
        for (int rt = 0; rt < 2; ++rt) {
            long long row = rowbase + rt * 16 + lrow;
            float4 v0 = {0.f,0.f,0.f,0.f}, v1 = {0.f,0.f,0.f,0.f};
            if (row < n) {
                const float* xp = x + row * DIN + k0;
                v0 = *(const float4*)xp;
                v1 = *(const float4*)(xp + 4);
            }
            short8 av;
            av[0] = f2bf(v0.x); av[1] = f2bf(v0.y); av[2] = f2bf(v0.z); av[3] = f2bf(v0.w);
            av[4] = f2bf(v1.x); av[5] = f2bf(v1.y); av[6] = f2bf(v1.z); av[7] = f2bf(v1.w);
            a[rt] = av;
        }
        #pragma unroll
        for (int nt = 0; nt < 8; ++nt) {
            short8 b = lf[(kt * 8 + nt) * 64 + lane];
            acc[0][nt] = __builtin_amdgcn_mfma_f32_16x16x32_bf16(a[0], b, acc[0][nt], 0, 0, 0);
            acc[1][nt] = __builtin_amdgcn_mfma_f32_16x16x32_bf16(a[1], b, acc[1][nt], 0, 0, 0);
        }
    }
    #pragma unroll
    for (int rt = 0; rt < 2; ++rt)
        #pragma unroll
        for (int nt = 0; nt < 8; ++nt)
            #pragma unroll
            for (int r = 0; r < 4; ++r) {
                long long row = rowbase + rt * 16 + quad * 4 + r;
                if (row < n) hb[row * DHID + nt * 16 + lrow] = f2bf(acc[rt][nt][r]);
            }
}

// ===== gather layer 1 (bf16 h in, bf16 h1 out, 4x unroll, fused epilogue) ==
__global__ void k_gather1(const int* __restrict__ beg, const int* __restrict__ degi,
                          const int* __restrict__ ssrc, const float* __restrict__ dinv,
                          const unsigned int* __restrict__ hu, const float* __restrict__ b1,
                          unsigned int* __restrict__ h1u, int n) {
    int node = blockIdx.x * 4 + (threadIdx.x >> 6);
    int t = threadIdx.x & 63;
    if (node >= n) return;
    int cnt = degi[node];
    int bg  = beg[node];
    float ax = 0.f, ay = 0.f;
    int k = 0;
    for (; k + 4 <= cnt; k += 4) {
        int s0 = ssrc[bg + k + 0], s1 = ssrc[bg + k + 1];
        int s2 = ssrc[bg + k + 2], s3 = ssrc[bg + k + 3];
        float d0 = dinv[s0], d1 = dinv[s1], d2 = dinv[s2], d3 = dinv[s3];
        unsigned int u0 = hu[(size_t)s0 * 64 + t];
        unsigned int u1 = hu[(size_t)s1 * 64 + t];
        unsigned int u2 = hu[(size_t)s2 * 64 + t];
        unsigned int u3 = hu[(size_t)s3 * 64 + t];
        ax += d0 * bfu(u0) + d1 * bfu(u1) + d2 * bfu(u2) + d3 * bfu(u3);
        ay += d0 * __uint_as_float(u0 & 0xffff0000u) + d1 * __uint_as_float(u1 & 0xffff0000u)
            + d2 * __uint_as_float(u2 & 0xffff0000u) + d3 * __uint_as_float(u3 & 0xffff0000u);
    }
    for (; k < cnt; ++k) {
        int s = ssrc[bg + k];
        float ds = dinv[s];
        unsigned int u = hu[(size_t)s * 64 + t];
        ax += ds * bfu(u);
        ay += ds * __uint_as_float(u & 0xffff0000u);
    }
    float di = dinv[node];
    unsigned int us = hu[(size_t)node * 64 + t];
    float2 bb = ((const float2*)b1)[t];
    float vx = di * ax + bfu(us) * di * di + bb.x;
    float vy = di * ay + __uint_as_float(us & 0xffff0000u) * di * di + bb.y;
    vx = vx > 0.f ? vx : 0.f;
    vy = vy > 0.f ? vy : 0.f;
    unsigned int o = (unsigned int)(unsigned short)f2bf(vx)
                   | ((unsigned int)(unsigned short)f2bf(vy) << 16);
    h1u[(size_t)node * 64 + t] = o;
}

// ========== GEMM2 via MFMA: h2b[n,64] = bf16(h1b[n,128] @ W2pad) ===========
__global__ __launch_bounds__(256) void k_gemm2_mfma(const short* __restrict__ h1b,
                                                    const short* __restrict__ W2s,
                                                    short* __restrict__ h2b, int n) {
    __shared__ short lw[8192];  // 16 KB: swizzled padded W2
    {
        const uint4* g = (const uint4*)W2s;
        uint4* l = (uint4*)lw;
        for (int i = threadIdx.x; i < 1024; i += 256) l[i] = g[i];
    }
    __syncthreads();

    int wave = threadIdx.x >> 6, lane = threadIdx.x & 63;
    int quad = lane >> 4, lrow = lane & 15;
    long long row0 = (long long)blockIdx.x * 64 + wave * 16;

    f32x4 acc[4];
    #pragma unroll
    for (int nt = 0; nt < 4; ++nt) acc[nt] = (f32x4){0.f, 0.f, 0.f, 0.f};

    const short8* lf = (const short8*)lw;

    #pragma unroll
    for (int kt = 0; kt < 4; ++kt) {
        long long row = row0 + lrow;
        short8 a = (short8){0,0,0,0,0,0,0,0};
        if (row < n) a = *(const short8*)(h1b + row * DHID + kt * 32 + quad * 8);
        #pragma unroll
        for (int nt = 0; nt < 4; ++nt)
            acc[nt] = __builtin_amdgcn_mfma_f32_16x16x32_bf16(a, lf[(kt * 4 + nt) * 64 + lane], acc[nt], 0, 0, 0);
    }
    #pragma unroll
    for (int nt = 0; nt < 4; ++nt)
        #pragma unroll
        for (int r = 0; r < 4; ++r) {
            long long row = row0 + quad * 4 + r;
            if (row < n) h2b[row * 64 + nt * 16 + lrow] = f2bf(acc[nt][r]);
        }
}

// ===== gather layer 2 (bf16 padded h2, 4x unroll, fused epilogue) ==========
__global__ void k_gather2(const int* __restrict__ beg, const int* __restrict__ degi,
                          const int* __restrict__ ssrc, const float* __restrict__ dinv,
                          const unsigned short* __restrict__ h2b, const float* __restrict__ b2,
                          float* __restrict__ out, int n) {
    int node = blockIdx.x * 4 + (threadIdx.x >> 6);
    int t = threadIdx.x & 63;
    if (node >= n) return;
    int cnt = degi[node];
    int bg  = beg[node];
    float acc = 0.f;
    int k = 0;
    for (; k + 4 <= cnt; k += 4) {
        int s0 = ssrc[bg + k + 0], s1 = ssrc[bg + k + 1];
        int s2 = ssrc[bg + k + 2], s3 = ssrc[bg + k + 3];
        float d0 = dinv[s0], d1 = dinv[s1], d2 = dinv[s2], d3 = dinv[s3];
        unsigned int u0 = h2b[(size_t)s0 * 64 + t];
        unsigned int u1 = h2b[(size_t)s1 * 64 + t];
        unsigned int u2 = h2b[(size_t)s2 * 64 + t];
        unsigned int u3 = h2b[(size_t)s3 * 64 + t];
        acc += d0 * bfu(u0) + d1 * bfu(u1) + d2 * bfu(u2) + d3 * bfu(u3);
    }
    for (; k < cnt; ++k) {
        int s = ssrc[bg + k];
        acc += dinv[s] * bfu((unsigned int)h2b[(size_t)s * 64 + t]);
    }
    if (t < NCLS) {
        float di = dinv[node];
        float self = bfu((unsigned int)h2b[(size_t)node * 64 + t]);
        out[(size_t)node * NCLS + t] = di * acc + self * di * di + b2[t];
    }
}

// ===========================================================================
extern "C" void kernel_launch(void* const* d_in, const int* in_sizes, int n_in,
                              void* d_out, int out_size, void* d_ws, size_t ws_size,
                              hipStream_t stream) {
    const float* x  = (const float*)d_in[0];
    const int*   ei = (const int*)d_in[1];
    const float* W1 = (const float*)d_in[2];
    const float* b1 = (const float*)d_in[3];
    const float* W2 = (const float*)d_in[4];
    const float* b2 = (const float*)d_in[5];

    const int n = in_sizes[0] / DIN;   // 100000
    const int E = in_sizes[1] / 2;     // 1600000
    const int* src = ei;
    const int* dst = ei + E;
    float* out = (float*)d_out;

    const int NB = (n + 127) >> 7;     // 782 buckets

    // workspace layout (~78 MB)
    char* w = (char*)d_ws;
    int*   bcnt = (int*)w;                     w += ((size_t)NB * 4 + 15) & ~15ull;
    int*   degi = (int*)w;                     w += (size_t)n * 4;
    int*   beg  = (int*)w;                     w += (size_t)n * 4;
    float* dinv = (float*)w;                   w += (size_t)n * 4;
    short* W1s  = (short*)w;                   w += (size_t)32768 * 2;        // 64 KB
    short* W2s  = (short*)w;                   w += (size_t)8192 * 2;         // 16 KB
    unsigned int* bbuf = (unsigned int*)w;     w += (size_t)NB * BCAP * 4;    // 12.8 MB, becomes ssrc
    short* hb   = (short*)w;                   w += (size_t)n * DHID * 2;     // bf16 x@W1
    short* h1b  = (short*)w;                   w += (size_t)n * DHID * 2;     // bf16 relu layer1
    short* h2b  = (short*)w;                   w += (size_t)n * 64 * 2;       // bf16 h1@W2, N-pad 64

    // 1. CSR build (bucket sort) + weight swizzles
    hipMemsetAsync(bcnt, 0, (size_t)NB * sizeof(int), stream);
    k_prepW1<<<16, 256, 0, stream>>>(W1, W1s);
    k_prepW2<<<4, 256, 0, stream>>>(W2, W2s);
    k_bucket<<<(E + 255) / 256, 256, 0, stream>>>(src, dst, bcnt, bbuf, E);
    k_bsort<<<NB, 256, 0, stream>>>(bcnt, bbuf, degi, beg, dinv, n);

    // 2. layer 1: MFMA transform -> gather (fused bias+self+relu, bf16 out)
    k_gemm1_mfma<<<(n + 127) / 128, 256, 0, stream>>>(x, W1s, hb, n);
    k_gather1<<<(n + 3) / 4, 256, 0, stream>>>(beg, degi, (const int*)bbuf, dinv,
                                               (const unsigned int*)hb, b1,
                                               (unsigned int*)h1b, n);

    // 3. layer 2: MFMA transform -> gather (fused bias+self)
    k_gemm2_mfma<<<(n + 63) / 64, 256, 0, stream>>>(h1b, W2s, h2b, n);
    k_gather2<<<(n + 3) / 4, 256, 0, stream>>>(beg, degi, (const int*)bbuf, dinv,
                                               (const unsigned short*)h2b, b2, out, n);
}

// Round 6
// 531.230 us; speedup vs baseline: 1.4157x; 1.4157x over previous
//
#include <hip/hip_runtime.h>
#include <hip/hip_bf16.h>

#define DIN 256
#define DHID 128
#define NCLS 47
#define BSHIFT 9                 // bucket = dst >> 9  (512 nodes/bucket)
#define BNODES 512
#define NPART 256                // edge partitions (one histogram each)
#define BCAPS 9216               // per-bucket LDS stage cap (lambda 8192 + 11 sigma)

typedef __attribute__((ext_vector_type(8))) short short8;   // 8 bf16 (4 VGPRs)
typedef __attribute__((ext_vector_type(4))) float f32x4;

__device__ __forceinline__ short f2bf(float f) {
    __bf16 b = (__bf16)f;                 // RNE convert
    return __builtin_bit_cast(short, b);
}
__device__ __forceinline__ float bfu(unsigned int u) {   // low 16 bits = bf16
    return __uint_as_float(u << 16);
}

// ============ CSR build pass 1: per-partition bucket histograms ============
__global__ __launch_bounds__(256) void k_hist(const int* __restrict__ dst,
                                              int* __restrict__ ghist,
                                              int E, int NB, int chunk) {
    extern __shared__ int lh[];   // NB counters
    int blk = blockIdx.x, t = threadIdx.x;
    for (int i = t; i < NB; i += 256) lh[i] = 0;
    __syncthreads();
    int lo = blk * chunk, hi = min(E, lo + chunk);
    for (int i = lo + t; i < hi; i += 256)
        atomicAdd(&lh[dst[i] >> BSHIFT], 1);
    __syncthreads();
    for (int i = t; i < NB; i += 256) ghist[blk * NB + i] = lh[i];
}

// ============ CSR build pass 2: exact offsets (single block) ===============
// goff[wg][b] = base[b] + sum_{wg'<wg} ghist[wg'][b];  base = excl scan of totals
__global__ __launch_bounds__(256) void k_offsets(const int* __restrict__ ghist,
                                                 int* __restrict__ goff,
                                                 int* __restrict__ base,
                                                 int* __restrict__ btot, int NB) {
    __shared__ int tot[1024];
    int t = threadIdx.x;
    for (int b = t; b < NB; b += 256) {
        int run = 0;
        for (int wg = 0; wg < NPART; ++wg) {
            int v = ghist[wg * NB + b];
            goff[wg * NB + b] = run;   // relative for now
            run += v;
        }
        tot[b] = run;
    }
    __syncthreads();
    if (t == 0) {
        int run = 0;
        for (int b = 0; b < NB; ++b) { base[b] = run; btot[b] = tot[b]; run += tot[b]; }
    }
    __syncthreads();
    for (int b = t; b < NB; b += 256) {
        int bb = base[b];
        for (int wg = 0; wg < NPART; ++wg) goff[wg * NB + b] += bb;
    }
}

// ============ CSR build pass 3: scatter into bucket-grouped order ==========
// packed = src (17b) | (dst & 511) << 17 ; only LDS atomics
__global__ __launch_bounds__(256) void k_scatter(const int* __restrict__ src,
                                                 const int* __restrict__ dst,
                                                 const int* __restrict__ goff,
                                                 unsigned int* __restrict__ bbuf,
                                                 int E, int NB, int chunk) {
    extern __shared__ int lcur[];   // NB cursors
    int blk = blockIdx.x, t = threadIdx.x;
    for (int i = t; i < NB; i += 256) lcur[i] = goff[blk * NB + i];
    __syncthreads();
    int lo = blk * chunk, hi = min(E, lo + chunk);
    for (int i = lo + t; i < hi; i += 256) {
        int d = dst[i];
        int b = d >> BSHIFT;
        int pos = atomicAdd(&lcur[b], 1);
        bbuf[pos] = (unsigned int)src[i] | ((unsigned int)(d & (BNODES - 1)) << 17);
    }
}

// ========== CSR build pass 4: per-bucket counting sort (in place) ==========
__global__ __launch_bounds__(256) void k_bsort(const int* __restrict__ base,
                                               const int* __restrict__ btot,
                                               unsigned int* __restrict__ bbuf,
                                               int* __restrict__ degi,
                                               int* __restrict__ beg,
                                               float* __restrict__ dinv, int n) {
    __shared__ unsigned int stage[BCAPS];
    __shared__ int hist[BNODES];
    __shared__ int cur[BNODES];
    __shared__ int wsum[4];

    int b = blockIdx.x, t = threadIdx.x;
    int cnt = min(btot[b], BCAPS);
    int gbase = base[b];
    int node0 = b << BSHIFT;

    if (t < 128) { ((int2*)hist)[t] = (int2){0, 0}; ((int2*)hist)[t + 128] = (int2){0, 0}; }
    __syncthreads();

    for (int i = t; i < cnt; i += 256) {
        unsigned int p = bbuf[gbase + i];
        stage[i] = p;
        atomicAdd(&hist[p >> 17], 1);
    }
    __syncthreads();

    // exclusive scan of 512 counters: thread t owns pair (2t, 2t+1)
    int v0 = hist[2 * t], v1 = hist[2 * t + 1];
    int s = v0 + v1;
    int incl = s;
    int lane = t & 63, w = t >> 6;
    #pragma unroll
    for (int off = 1; off < 64; off <<= 1) {
        int u = __shfl_up(incl, off, 64);
        if (lane >= off) incl += u;
    }
    if (lane == 63) wsum[w] = incl;
    __syncthreads();
    int wadd = 0;
    for (int i = 0; i < w; ++i) wadd += wsum[i];
    int ex = wadd + incl - s;
    cur[2 * t] = ex;
    cur[2 * t + 1] = ex + v0;
    int nodeA = node0 + 2 * t, nodeB = node0 + 2 * t + 1;
    if (nodeA < n) {
        degi[nodeA] = v0;
        beg[nodeA]  = gbase + ex;
        dinv[nodeA] = rsqrtf((float)(v0 + 1));
    }
    if (nodeB < n) {
        degi[nodeB] = v1;
        beg[nodeB]  = gbase + ex + v0;
        dinv[nodeB] = rsqrtf((float)(v1 + 1));
    }
    __syncthreads();

    for (int i = t; i < cnt; i += 256) {
        unsigned int p = stage[i];
        int slot = atomicAdd(&cur[p >> 17], 1);
        bbuf[gbase + slot] = p & 0x1FFFFu;
    }
}

// ===================== W1 -> bf16 B-fragment swizzle =======================
__global__ void k_prepW1(const float* __restrict__ W1, short* __restrict__ W1s) {
    int tid = blockIdx.x * blockDim.x + threadIdx.x;   // 0..4095
    int frag = tid >> 6, lane = tid & 63;
    int kt = frag >> 3, nt = frag & 7;
    int quad = lane >> 4, col = lane & 15;
    #pragma unroll
    for (int j = 0; j < 8; ++j) {
        int k = kt * 32 + quad * 8 + j;
        W1s[(size_t)tid * 8 + j] = f2bf(W1[k * DHID + nt * 16 + col]);
    }
}

// ===================== W2 -> bf16 B-fragment swizzle (pad N to 64) =========
__global__ void k_prepW2(const float* __restrict__ W2, short* __restrict__ W2s) {
    int tid = blockIdx.x * blockDim.x + threadIdx.x;   // 0..1023
    int frag = tid >> 6, lane = tid & 63;
    int kt = frag >> 2, nt = frag & 3;
    int quad = lane >> 4, col = lane & 15;
    int c = nt * 16 + col;
    #pragma unroll
    for (int j = 0; j < 8; ++j) {
        int k = kt * 32 + quad * 8 + j;
        float v = (c < NCLS) ? W2[k * NCLS + c] : 0.0f;
        W2s[(size_t)tid * 8 + j] = f2bf(v);
    }
}

// ===================== GEMM1 via MFMA: hb = bf16(x @ W1) ===================
__global__ __launch_bounds__(256) void k_gemm1_mfma(const float* __restrict__ x,
                                                    const short* __restrict__ W1s,
                                                    short* __restrict__ hb, int n) {
    __shared__ short lw[32768];  // 64 KB: full swizzled W1
    {
        const uint4* g = (const uint4*)W1s;
        uint4* l = (uint4*)lw;
        for (int i = threadIdx.x; i < 4096; i += 256) l[i] = g[i];
    }
    __syncthreads();

    int wave = threadIdx.x >> 6, lane = threadIdx.x & 63;
    int quad = lane >> 4, lrow = lane & 15;
    long long rowbase = (long long)blockIdx.x * 128 + wave * 32;

    f32x4 acc[2][8];
    #pragma unroll
    for (int rt = 0; rt < 2; ++rt)
        #pragma unroll
        for (int nt = 0; nt < 8; ++nt) acc[rt][nt] = (f32x4){0.f, 0.f, 0.f, 0.f};

    const short8* lf = (const short8*)lw;

    #pragma unroll
    for (int kt = 0; kt < 8; ++kt) {
        int k0 = kt * 32 + quad * 8;
        short8 a[2];
        #pragma unroll
        for (int rt = 0; rt < 2; ++rt) {
            long long row = rowbase + rt * 16 + lrow;
            float4 v0 = {0.f,0.f,0.f,0.f}, v1 = {0.f,0.f,0.f,0.f};
            if (row < n) {
                const float* xp = x + row * DIN + k0;
                v0 = *(const float4*)xp;
                v1 = *(const float4*)(xp + 4);
            }
            short8 av;
            av[0] = f2bf(v0.x); av[1] = f2bf(v0.y); av[2] = f2bf(v0.z); av[3] = f2bf(v0.w);
            av[4] = f2bf(v1.x); av[5] = f2bf(v1.y); av[6] = f2bf(v1.z); av[7] = f2bf(v1.w);
            a[rt] = av;
        }
        #pragma unroll
        for (int nt = 0; nt < 8; ++nt) {
            short8 b = lf[(kt * 8 + nt) * 64 + lane];
            acc[0][nt] = __builtin_amdgcn_mfma_f32_16x16x32_bf16(a[0], b, acc[0][nt], 0, 0, 0);
            acc[1][nt] = __builtin_amdgcn_mfma_f32_16x16x32_bf16(a[1], b, acc[1][nt], 0, 0, 0);
        }
    }
    #pragma unroll
    for (int rt = 0; rt < 2; ++rt)
        #pragma unroll
        for (int nt = 0; nt < 8; ++nt)
            #pragma unroll
            for (int r = 0; r < 4; ++r) {
                long long row = rowbase + rt * 16 + quad * 4 + r;
                if (row < n) hb[row * DHID + nt * 16 + lrow] = f2bf(acc[rt][nt][r]);
            }
}

// ===== gather layer 1 (bf16 h in, bf16 h1 out, 4x unroll, fused epilogue) ==
__global__ void k_gather1(const int* __restrict__ beg, const int* __restrict__ degi,
                          const int* __restrict__ ssrc, const float* __restrict__ dinv,
                          const unsigned int* __restrict__ hu, const float* __restrict__ b1,
                          unsigned int* __restrict__ h1u, int n) {
    int node = blockIdx.x * 4 + (threadIdx.x >> 6);
    int t = threadIdx.x & 63;
    if (node >= n) return;
    int cnt = degi[node];
    int bg  = beg[node];
    float ax = 0.f, ay = 0.f;
    int k = 0;
    for (; k + 4 <= cnt; k += 4) {
        int s0 = ssrc[bg + k + 0], s1 = ssrc[bg + k + 1];
        int s2 = ssrc[bg + k + 2], s3 = ssrc[bg + k + 3];
        float d0 = dinv[s0], d1 = dinv[s1], d2 = dinv[s2], d3 = dinv[s3];
        unsigned int u0 = hu[(size_t)s0 * 64 + t];
        unsigned int u1 = hu[(size_t)s1 * 64 + t];
        unsigned int u2 = hu[(size_t)s2 * 64 + t];
        unsigned int u3 = hu[(size_t)s3 * 64 + t];
        ax += d0 * bfu(u0) + d1 * bfu(u1) + d2 * bfu(u2) + d3 * bfu(u3);
        ay += d0 * __uint_as_float(u0 & 0xffff0000u) + d1 * __uint_as_float(u1 & 0xffff0000u)
            + d2 * __uint_as_float(u2 & 0xffff0000u) + d3 * __uint_as_float(u3 & 0xffff0000u);
    }
    for (; k < cnt; ++k) {
        int s = ssrc[bg + k];
        float ds = dinv[s];
        unsigned int u = hu[(size_t)s * 64 + t];
        ax += ds * bfu(u);
        ay += ds * __uint_as_float(u & 0xffff0000u);
    }
    float di = dinv[node];
    unsigned int us = hu[(size_t)node * 64 + t];
    float2 bb = ((const float2*)b1)[t];
    float vx = di * ax + bfu(us) * di * di + bb.x;
    float vy = di * ay + __uint_as_float(us & 0xffff0000u) * di * di + bb.y;
    vx = vx > 0.f ? vx : 0.f;
    vy = vy > 0.f ? vy : 0.f;
    unsigned int o = (unsigned int)(unsigned short)f2bf(vx)
                   | ((unsigned int)(unsigned short)f2bf(vy) << 16);
    h1u[(size_t)node * 64 + t] = o;
}

// ========== GEMM2 via MFMA: h2b[n,64] = bf16(h1b[n,128] @ W2pad) ===========
__global__ __launch_bounds__(256) void k_gemm2_mfma(const short* __restrict__ h1b,
                                                    const short* __restrict__ W2s,
                                                    short* __restrict__ h2b, int n) {
    __shared__ short lw[8192];  // 16 KB: swizzled padded W2
    {
        const uint4* g = (const uint4*)W2s;
        uint4* l = (uint4*)lw;
        for (int i = threadIdx.x; i < 1024; i += 256) l[i] = g[i];
    }
    __syncthreads();

    int wave = threadIdx.x >> 6, lane = threadIdx.x & 63;
    int quad = lane >> 4, lrow = lane & 15;
    long long row0 = (long long)blockIdx.x * 64 + wave * 16;

    f32x4 acc[4];
    #pragma unroll
    for (int nt = 0; nt < 4; ++nt) acc[nt] = (f32x4){0.f, 0.f, 0.f, 0.f};

    const short8* lf = (const short8*)lw;

    #pragma unroll
    for (int kt = 0; kt < 4; ++kt) {
        long long row = row0 + lrow;
        short8 a = (short8){0,0,0,0,0,0,0,0};
        if (row < n) a = *(const short8*)(h1b + row * DHID + kt * 32 + quad * 8);
        #pragma unroll
        for (int nt = 0; nt < 4; ++nt)
            acc[nt] = __builtin_amdgcn_mfma_f32_16x16x32_bf16(a, lf[(kt * 4 + nt) * 64 + lane], acc[nt], 0, 0, 0);
    }
    #pragma unroll
    for (int nt = 0; nt < 4; ++nt)
        #pragma unroll
        for (int r = 0; r < 4; ++r) {
            long long row = row0 + quad * 4 + r;
            if (row < n) h2b[row * 64 + nt * 16 + lrow] = f2bf(acc[nt][r]);
        }
}

// ===== gather layer 2 (bf16 padded h2, 4x unroll, fused epilogue) ==========
__global__ void k_gather2(const int* __restrict__ beg, const int* __restrict__ degi,
                          const int* __restrict__ ssrc, const float* __restrict__ dinv,
                          const unsigned short* __restrict__ h2b, const float* __restrict__ b2,
                          float* __restrict__ out, int n) {
    int node = blockIdx.x * 4 + (threadIdx.x >> 6);
    int t = threadIdx.x & 63;
    if (node >= n) return;
    int cnt = degi[node];
    int bg  = beg[node];
    float acc = 0.f;
    int k = 0;
    for (; k + 4 <= cnt; k += 4) {
        int s0 = ssrc[bg + k + 0], s1 = ssrc[bg + k + 1];
        int s2 = ssrc[bg + k + 2], s3 = ssrc[bg + k + 3];
        float d0 = dinv[s0], d1 = dinv[s1], d2 = dinv[s2], d3 = dinv[s3];
        unsigned int u0 = h2b[(size_t)s0 * 64 + t];
        unsigned int u1 = h2b[(size_t)s1 * 64 + t];
        unsigned int u2 = h2b[(size_t)s2 * 64 + t];
        unsigned int u3 = h2b[(size_t)s3 * 64 + t];
        acc += d0 * bfu(u0) + d1 * bfu(u1) + d2 * bfu(u2) + d3 * bfu(u3);
    }
    for (; k < cnt; ++k) {
        int s = ssrc[bg + k];
        acc += dinv[s] * bfu((unsigned int)h2b[(size_t)s * 64 + t]);
    }
    if (t < NCLS) {
        float di = dinv[node];
        float self = bfu((unsigned int)h2b[(size_t)node * 64 + t]);
        out[(size_t)node * NCLS + t] = di * acc + self * di * di + b2[t];
    }
}

// ===========================================================================
extern "C" void kernel_launch(void* const* d_in, const int* in_sizes, int n_in,
                              void* d_out, int out_size, void* d_ws, size_t ws_size,
                              hipStream_t stream) {
    const float* x  = (const float*)d_in[0];
    const int*   ei = (const int*)d_in[1];
    const float* W1 = (const float*)d_in[2];
    const float* b1 = (const float*)d_in[3];
    const float* W2 = (const float*)d_in[4];
    const float* b2 = (const float*)d_in[5];

    const int n = in_sizes[0] / DIN;   // 100000
    const int E = in_sizes[1] / 2;     // 1600000
    const int* src = ei;
    const int* dst = ei + E;
    float* out = (float*)d_out;

    const int NB = (n + BNODES - 1) >> BSHIFT;   // 196 buckets
    const int chunk = (E + NPART - 1) / NPART;   // 6250

    // workspace layout (~72 MB)
    char* w = (char*)d_ws;
    int*   ghist = (int*)w;                    w += (size_t)NPART * NB * 4;   // 200 KB
    int*   goff  = (int*)w;                    w += (size_t)NPART * NB * 4;   // 200 KB
    int*   base  = (int*)w;                    w += ((size_t)NB * 4 + 15) & ~15ull;
    int*   btot  = (int*)w;                    w += ((size_t)NB * 4 + 15) & ~15ull;
    int*   degi  = (int*)w;                    w += (size_t)n * 4;
    int*   beg   = (int*)w;                    w += (size_t)n * 4;
    float* dinv  = (float*)w;                  w += (size_t)n * 4;
    short* W1s   = (short*)w;                  w += (size_t)32768 * 2;        // 64 KB
    short* W2s   = (short*)w;                  w += (size_t)8192 * 2;         // 16 KB
    unsigned int* bbuf = (unsigned int*)w;     w += (size_t)E * 4;            // 6.4 MB -> ssrc
    short* hb    = (short*)w;                  w += (size_t)n * DHID * 2;     // bf16 x@W1
    short* h1b   = (short*)w;                  w += (size_t)n * DHID * 2;     // bf16 relu layer1
    short* h2b   = (short*)w;                  w += (size_t)n * 64 * 2;       // bf16 h1@W2, N-pad 64

    // 1. CSR build (no global atomics) + weight swizzles
    k_prepW1<<<16, 256, 0, stream>>>(W1, W1s);
    k_prepW2<<<4, 256, 0, stream>>>(W2, W2s);
    k_hist<<<NPART, 256, NB * 4, stream>>>(dst, ghist, E, NB, chunk);
    k_offsets<<<1, 256, 0, stream>>>(ghist, goff, base, btot, NB);
    k_scatter<<<NPART, 256, NB * 4, stream>>>(src, dst, goff, bbuf, E, NB, chunk);
    k_bsort<<<NB, 256, 0, stream>>>(base, btot, bbuf, degi, beg, dinv, n);

    // 2. layer 1: MFMA transform -> gather (fused bias+self+relu, bf16 out)
    k_gemm1_mfma<<<(n + 127) / 128, 256, 0, stream>>>(x, W1s, hb, n);
    k_gather1<<<(n + 3) / 4, 256, 0, stream>>>(beg, degi, (const int*)bbuf, dinv,
                                               (const unsigned int*)hb, b1,
                                               (unsigned int*)h1b, n);

    // 3. layer 2: MFMA transform -> gather (fused bias+self)
    k_gemm2_mfma<<<(n + 63) / 64, 256, 0, stream>>>(h1b, W2s, h2b, n);
    k_gather2<<<(n + 3) / 4, 256, 0, stream>>>(beg, degi, (const int*)bbuf, dinv,
                                               (const unsigned short*)h2b, b2, out, n);
}

// Round 7
// 423.898 us; speedup vs baseline: 1.7741x; 1.2532x over previous
//
#include <hip/hip_runtime.h>
#include <hip/hip_bf16.h>

#define DIN 256
#define DHID 128
#define NCLS 47
#define BSHIFT 9                 // bucket = dst >> 9  (512 nodes/bucket)
#define BNODES 512
#define NPART 256                // edge partitions (one histogram each)
#define BCAPS 9216               // per-bucket LDS stage cap (lambda 8192 + 11 sigma)

typedef __attribute__((ext_vector_type(8))) short short8;   // 8 bf16 (4 VGPRs)
typedef __attribute__((ext_vector_type(4))) float f32x4;

__device__ __forceinline__ short f2bf(float f) {
    __bf16 b = (__bf16)f;                 // RNE convert
    return __builtin_bit_cast(short, b);
}
__device__ __forceinline__ float bfu(unsigned int u) {   // low 16 bits = bf16
    return __uint_as_float(u << 16);
}

// ============ CSR build pass 1: per-partition bucket histograms ============
__global__ __launch_bounds__(256) void k_hist(const int* __restrict__ dst,
                                              int* __restrict__ ghist,
                                              int E, int NB, int chunk) {
    extern __shared__ int lh[];   // NB counters
    int blk = blockIdx.x, t = threadIdx.x;
    for (int i = t; i < NB; i += 256) lh[i] = 0;
    __syncthreads();
    int lo = blk * chunk, hi = min(E, lo + chunk);
    for (int i = lo + t; i < hi; i += 256)
        atomicAdd(&lh[dst[i] >> BSHIFT], 1);
    __syncthreads();
    for (int i = t; i < NB; i += 256) ghist[blk * NB + i] = lh[i];
}

// ============ CSR build pass 2a: per-bucket column scan (parallel) =========
// block b: goff[wg][b] = sum_{wg'<wg} ghist[wg'][b] (relative); btot[b] = total
__global__ __launch_bounds__(256) void k_colscan(const int* __restrict__ ghist,
                                                 int* __restrict__ goff,
                                                 int* __restrict__ btot, int NB) {
    __shared__ int wsum[4];
    int b = blockIdx.x, t = threadIdx.x;
    int v = ghist[t * NB + b];
    int incl = v;
    int lane = t & 63, w = t >> 6;
    #pragma unroll
    for (int off = 1; off < 64; off <<= 1) {
        int u = __shfl_up(incl, off, 64);
        if (lane >= off) incl += u;
    }
    if (lane == 63) wsum[w] = incl;
    __syncthreads();
    int wadd = 0;
    for (int i = 0; i < w; ++i) wadd += wsum[i];
    goff[t * NB + b] = wadd + incl - v;      // exclusive prefix (relative)
    if (t == 255) btot[b] = wadd + incl;     // column total
}

// ============ CSR build pass 2b: scan bucket totals (tiny) =================
__global__ __launch_bounds__(256) void k_basescan(const int* __restrict__ btot,
                                                  int* __restrict__ base, int NB) {
    __shared__ int wsum[4];
    int t = threadIdx.x;
    int v = (t < NB) ? btot[t] : 0;
    int incl = v;
    int lane = t & 63, w = t >> 6;
    #pragma unroll
    for (int off = 1; off < 64; off <<= 1) {
        int u = __shfl_up(incl, off, 64);
        if (lane >= off) incl += u;
    }
    if (lane == 63) wsum[w] = incl;
    __syncthreads();
    int wadd = 0;
    for (int i = 0; i < w; ++i) wadd += wsum[i];
    if (t < NB) base[t] = wadd + incl - v;   // exclusive
}

// ============ CSR build pass 3: scatter into bucket-grouped order ==========
// packed = src (17b) | (dst & 511) << 17 ; only LDS atomics
__global__ __launch_bounds__(256) void k_scatter(const int* __restrict__ src,
                                                 const int* __restrict__ dst,
                                                 const int* __restrict__ goff,
                                                 const int* __restrict__ base,
                                                 unsigned int* __restrict__ bbuf,
                                                 int E, int NB, int chunk) {
    extern __shared__ int lcur[];   // NB cursors
    int blk = blockIdx.x, t = threadIdx.x;
    for (int i = t; i < NB; i += 256) lcur[i] = goff[blk * NB + i] + base[i];
    __syncthreads();
    int lo = blk * chunk, hi = min(E, lo + chunk);
    for (int i = lo + t; i < hi; i += 256) {
        int d = dst[i];
        int b = d >> BSHIFT;
        int pos = atomicAdd(&lcur[b], 1);
        bbuf[pos] = (unsigned int)src[i] | ((unsigned int)(d & (BNODES - 1)) << 17);
    }
}

// ========== CSR build pass 4: per-bucket counting sort (in place) ==========
__global__ __launch_bounds__(256) void k_bsort(const int* __restrict__ base,
                                               const int* __restrict__ btot,
                                               unsigned int* __restrict__ bbuf,
                                               int* __restrict__ degi,
                                               int* __restrict__ beg,
                                               float* __restrict__ dinv, int n) {
    __shared__ unsigned int stage[BCAPS];
    __shared__ int hist[BNODES];
    __shared__ int cur[BNODES];
    __shared__ int wsum[4];

    int b = blockIdx.x, t = threadIdx.x;
    int cnt = min(btot[b], BCAPS);
    int gbase = base[b];
    int node0 = b << BSHIFT;

    if (t < 128) { ((int2*)hist)[t] = (int2){0, 0}; ((int2*)hist)[t + 128] = (int2){0, 0}; }
    __syncthreads();

    for (int i = t; i < cnt; i += 256) {
        unsigned int p = bbuf[gbase + i];
        stage[i] = p;
        atomicAdd(&hist[p >> 17], 1);
    }
    __syncthreads();

    // exclusive scan of 512 counters: thread t owns pair (2t, 2t+1)
    int v0 = hist[2 * t], v1 = hist[2 * t + 1];
    int s = v0 + v1;
    int incl = s;
    int lane = t & 63, w = t >> 6;
    #pragma unroll
    for (int off = 1; off < 64; off <<= 1) {
        int u = __shfl_up(incl, off, 64);
        if (lane >= off) incl += u;
    }
    if (lane == 63) wsum[w] = incl;
    __syncthreads();
    int wadd = 0;
    for (int i = 0; i < w; ++i) wadd += wsum[i];
    int ex = wadd + incl - s;
    cur[2 * t] = ex;
    cur[2 * t + 1] = ex + v0;
    int nodeA = node0 + 2 * t, nodeB = node0 + 2 * t + 1;
    if (nodeA < n) {
        degi[nodeA] = v0;
        beg[nodeA]  = gbase + ex;
        dinv[nodeA] = rsqrtf((float)(v0 + 1));
    }
    if (nodeB < n) {
        degi[nodeB] = v1;
        beg[nodeB]  = gbase + ex + v0;
        dinv[nodeB] = rsqrtf((float)(v1 + 1));
    }
    __syncthreads();

    for (int i = t; i < cnt; i += 256) {
        unsigned int p = stage[i];
        int slot = atomicAdd(&cur[p >> 17], 1);
        bbuf[gbase + slot] = p & 0x1FFFFu;
    }
}

// ===================== W1 -> bf16 B-fragment swizzle =======================
__global__ void k_prepW1(const float* __restrict__ W1, short* __restrict__ W1s) {
    int tid = blockIdx.x * blockDim.x + threadIdx.x;   // 0..4095
    int frag = tid >> 6, lane = tid & 63;
    int kt = frag >> 3, nt = frag & 7;
    int quad = lane >> 4, col = lane & 15;
    #pragma unroll
    for (int j = 0; j < 8; ++j) {
        int k = kt * 32 + quad * 8 + j;
        W1s[(size_t)tid * 8 + j] = f2bf(W1[k * DHID + nt * 16 + col]);
    }
}

// ===================== W2 -> bf16 B-fragment swizzle (pad N to 64) =========
__global__ void k_prepW2(const float* __restrict__ W2, short* __restrict__ W2s) {
    int tid = blockIdx.x * blockDim.x + threadIdx.x;   // 0..1023
    int frag = tid >> 6, lane = tid & 63;
    int kt = frag >> 2, nt = frag & 3;
    int quad = lane >> 4, col = lane & 15;
    int c = nt * 16 + col;
    #pragma unroll
    for (int j = 0; j < 8; ++j) {
        int k = kt * 32 + quad * 8 + j;
        float v = (c < NCLS) ? W2[k * NCLS + c] : 0.0f;
        W2s[(size_t)tid * 8 + j] = f2bf(v);
    }
}

// ===================== GEMM1 via MFMA: hb = bf16(x @ W1) ===================
__global__ __launch_bounds__(256) void k_gemm1_mfma(const float* __restrict__ x,
                                                    const short* __restrict__ W1s,
                                                    short* __restrict__ hb, int n) {
    __shared__ short lw[32768];  // 64 KB: full swizzled W1
    {
        const uint4* g = (const uint4*)W1s;
        uint4* l = (uint4*)lw;
        for (int i = threadIdx.x; i < 4096; i += 256) l[i] = g[i];
    }
    __syncthreads();

    int wave = threadIdx.x >> 6, lane = threadIdx.x & 63;
    int quad = lane >> 4, lrow = lane & 15;
    long long rowbase = (long long)blockIdx.x * 128 + wave * 32;

    f32x4 acc[2][8];
    #pragma unroll
    for (int rt = 0; rt < 2; ++rt)
        #pragma unroll
        for (int nt = 0; nt < 8; ++nt) acc[rt][nt] = (f32x4){0.f, 0.f, 0.f, 0.f};

    const short8* lf = (const short8*)lw;

    #pragma unroll
    for (int kt = 0; kt < 8; ++kt) {
        int k0 = kt * 32 + quad * 8;
        short8 a[2];
        #pragma unroll
        for (int rt = 0; rt < 2; ++rt) {
            long long row = rowbase + rt * 16 + lrow;
            float4 v0 = {0.f,0.f,0.f,0.f}, v1 = {0.f,0.f,0.f,0.f};
            if (row < n) {
                const float* xp = x + row * DIN + k0;
                v0 = *(const float4*)xp;
                v1 = *(const float4*)(xp + 4);
            }
            short8 av;
            av[0] = f2bf(v0.x); av[1] = f2bf(v0.y); av[2] = f2bf(v0.z); av[3] = f2bf(v0.w);
            av[4] = f2bf(v1.x); av[5] = f2bf(v1.y); av[6] = f2bf(v1.z); av[7] = f2bf(v1.w);
            a[rt] = av;
        }
        #pragma unroll
        for (int nt = 0; nt < 8; ++nt) {
            short8 b = lf[(kt * 8 + nt) * 64 + lane];
            acc[0][nt] = __builtin_amdgcn_mfma_f32_16x16x32_bf16(a[0], b, acc[0][nt], 0, 0, 0);
            acc[1][nt] = __builtin_amdgcn_mfma_f32_16x16x32_bf16(a[1], b, acc[1][nt], 0, 0, 0);
        }
    }
    #pragma unroll
    for (int rt = 0; rt < 2; ++rt)
        #pragma unroll
        for (int nt = 0; nt < 8; ++nt)
            #pragma unroll
            for (int r = 0; r < 4; ++r) {
                long long row = rowbase + rt * 16 + quad * 4 + r;
                if (row < n) hb[row * DHID + nt * 16 + lrow] = f2bf(acc[rt][nt][r]);
            }
}

// ===== gather layer 1 (bf16 h in, bf16 h1 out, 4x unroll, fused epilogue) ==
__global__ void k_gather1(const int* __restrict__ beg, const int* __restrict__ degi,
                          const int* __restrict__ ssrc, const float* __restrict__ dinv,
                          const unsigned int* __restrict__ hu, const float* __restrict__ b1,
                          unsigned int* __restrict__ h1u, int n) {
    int node = blockIdx.x * 4 + (threadIdx.x >> 6);
    int t = threadIdx.x & 63;
    if (node >= n) return;
    int cnt = degi[node];
    int bg  = beg[node];
    float ax = 0.f, ay = 0.f;
    int k = 0;
    for (; k + 4 <= cnt; k += 4) {
        int s0 = ssrc[bg + k + 0], s1 = ssrc[bg + k + 1];
        int s2 = ssrc[bg + k + 2], s3 = ssrc[bg + k + 3];
        float d0 = dinv[s0], d1 = dinv[s1], d2 = dinv[s2], d3 = dinv[s3];
        unsigned int u0 = hu[(size_t)s0 * 64 + t];
        unsigned int u1 = hu[(size_t)s1 * 64 + t];
        unsigned int u2 = hu[(size_t)s2 * 64 + t];
        unsigned int u3 = hu[(size_t)s3 * 64 + t];
        ax += d0 * bfu(u0) + d1 * bfu(u1) + d2 * bfu(u2) + d3 * bfu(u3);
        ay += d0 * __uint_as_float(u0 & 0xffff0000u) + d1 * __uint_as_float(u1 & 0xffff0000u)
            + d2 * __uint_as_float(u2 & 0xffff0000u) + d3 * __uint_as_float(u3 & 0xffff0000u);
    }
    for (; k < cnt; ++k) {
        int s = ssrc[bg + k];
        float ds = dinv[s];
        unsigned int u = hu[(size_t)s * 64 + t];
        ax += ds * bfu(u);
        ay += ds * __uint_as_float(u & 0xffff0000u);
    }
    float di = dinv[node];
    unsigned int us = hu[(size_t)node * 64 + t];
    float2 bb = ((const float2*)b1)[t];
    float vx = di * ax + bfu(us) * di * di + bb.x;
    float vy = di * ay + __uint_as_float(us & 0xffff0000u) * di * di + bb.y;
    vx = vx > 0.f ? vx : 0.f;
    vy = vy > 0.f ? vy : 0.f;
    unsigned int o = (unsigned int)(unsigned short)f2bf(vx)
                   | ((unsigned int)(unsigned short)f2bf(vy) << 16);
    h1u[(size_t)node * 64 + t] = o;
}

// ========== GEMM2 via MFMA: h2b[n,64] = bf16(h1b[n,128] @ W2pad) ===========
__global__ __launch_bounds__(256) void k_gemm2_mfma(const short* __restrict__ h1b,
                                                    const short* __restrict__ W2s,
                                                    short* __restrict__ h2b, int n) {
    __shared__ short lw[8192];  // 16 KB: swizzled padded W2
    {
        const uint4* g = (const uint4*)W2s;
        uint4* l = (uint4*)lw;
        for (int i = threadIdx.x; i < 1024; i += 256) l[i] = g[i];
    }
    __syncthreads();

    int wave = threadIdx.x >> 6, lane = threadIdx.x & 63;
    int quad = lane >> 4, lrow = lane & 15;
    long long row0 = (long long)blockIdx.x * 64 + wave * 16;

    f32x4 acc[4];
    #pragma unroll
    for (int nt = 0; nt < 4; ++nt) acc[nt] = (f32x4){0.f, 0.f, 0.f, 0.f};

    const short8* lf = (const short8*)lw;

    #pragma unroll
    for (int kt = 0; kt < 4; ++kt) {
        long long row = row0 + lrow;
        short8 a = (short8){0,0,0,0,0,0,0,0};
        if (row < n) a = *(const short8*)(h1b + row * DHID + kt * 32 + quad * 8);
        #pragma unroll
        for (int nt = 0; nt < 4; ++nt)
            acc[nt] = __builtin_amdgcn_mfma_f32_16x16x32_bf16(a, lf[(kt * 4 + nt) * 64 + lane], acc[nt], 0, 0, 0);
    }
    #pragma unroll
    for (int nt = 0; nt < 4; ++nt)
        #pragma unroll
        for (int r = 0; r < 4; ++r) {
            long long row = row0 + quad * 4 + r;
            if (row < n) h2b[row * 64 + nt * 16 + lrow] = f2bf(acc[nt][r]);
        }
}

// ===== gather layer 2 (bf16 padded h2, 4x unroll, fused epilogue) ==========
__global__ void k_gather2(const int* __restrict__ beg, const int* __restrict__ degi,
                          const int* __restrict__ ssrc, const float* __restrict__ dinv,
                          const unsigned short* __restrict__ h2b, const float* __restrict__ b2,
                          float* __restrict__ out, int n) {
    int node = blockIdx.x * 4 + (threadIdx.x >> 6);
    int t = threadIdx.x & 63;
    if (node >= n) return;
    int cnt = degi[node];
    int bg  = beg[node];
    float acc = 0.f;
    int k = 0;
    for (; k + 4 <= cnt; k += 4) {
        int s0 = ssrc[bg + k + 0], s1 = ssrc[bg + k + 1];
        int s2 = ssrc[bg + k + 2], s3 = ssrc[bg + k + 3];
        float d0 = dinv[s0], d1 = dinv[s1], d2 = dinv[s2], d3 = dinv[s3];
        unsigned int u0 = h2b[(size_t)s0 * 64 + t];
        unsigned int u1 = h2b[(size_t)s1 * 64 + t];
        unsigned int u2 = h2b[(size_t)s2 * 64 + t];
        unsigned int u3 = h2b[(size_t)s3 * 64 + t];
        acc += d0 * bfu(u0) + d1 * bfu(u1) + d2 * bfu(u2) + d3 * bfu(u3);
    }
    for (; k < cnt; ++k) {
        int s = ssrc[bg + k];
        acc += dinv[s] * bfu((unsigned int)h2b[(size_t)s * 64 + t]);
    }
    if (t < NCLS) {
        float di = dinv[node];
        float self = bfu((unsigned int)h2b[(size_t)node * 64 + t]);
        out[(size_t)node * NCLS + t] = di * acc + self * di * di + b2[t];
    }
}

// ===========================================================================
extern "C" void kernel_launch(void* const* d_in, const int* in_sizes, int n_in,
                              void* d_out, int out_size, void* d_ws, size_t ws_size,
                              hipStream_t stream) {
    const float* x  = (const float*)d_in[0];
    const int*   ei = (const int*)d_in[1];
    const float* W1 = (const float*)d_in[2];
    const float* b1 = (const float*)d_in[3];
    const float* W2 = (const float*)d_in[4];
    const float* b2 = (const float*)d_in[5];

    const int n = in_sizes[0] / DIN;   // 100000
    const int E = in_sizes[1] / 2;     // 1600000
    const int* src = ei;
    const int* dst = ei + E;
    float* out = (float*)d_out;

    const int NB = (n + BNODES - 1) >> BSHIFT;   // 196 buckets
    const int chunk = (E + NPART - 1) / NPART;   // 6250

    // workspace layout (~72 MB)
    char* w = (char*)d_ws;
    int*   ghist = (int*)w;                    w += (size_t)NPART * NB * 4;   // 200 KB
    int*   goff  = (int*)w;                    w += (size_t)NPART * NB * 4;   // 200 KB
    int*   base  = (int*)w;                    w += ((size_t)NB * 4 + 15) & ~15ull;
    int*   btot  = (int*)w;                    w += ((size_t)NB * 4 + 15) & ~15ull;
    int*   degi  = (int*)w;                    w += (size_t)n * 4;
    int*   beg   = (int*)w;                    w += (size_t)n * 4;
    float* dinv  = (float*)w;                  w += (size_t)n * 4;
    short* W1s   = (short*)w;                  w += (size_t)32768 * 2;        // 64 KB
    short* W2s   = (short*)w;                  w += (size_t)8192 * 2;         // 16 KB
    unsigned int* bbuf = (unsigned int*)w;     w += (size_t)E * 4;            // 6.4 MB -> ssrc
    short* hb    = (short*)w;                  w += (size_t)n * DHID * 2;     // bf16 x@W1
    short* h1b   = (short*)w;                  w += (size_t)n * DHID * 2;     // bf16 relu layer1
    short* h2b   = (short*)w;                  w += (size_t)n * 64 * 2;       // bf16 h1@W2, N-pad 64

    // 1. CSR build (no global atomics, parallel scans) + weight swizzles
    k_prepW1<<<16, 256, 0, stream>>>(W1, W1s);
    k_prepW2<<<4, 256, 0, stream>>>(W2, W2s);
    k_hist<<<NPART, 256, NB * 4, stream>>>(dst, ghist, E, NB, chunk);
    k_colscan<<<NB, 256, 0, stream>>>(ghist, goff, btot, NB);
    k_basescan<<<1, 256, 0, stream>>>(btot, base, NB);
    k_scatter<<<NPART, 256, NB * 4, stream>>>(src, dst, goff, base, bbuf, E, NB, chunk);
    k_bsort<<<NB, 256, 0, stream>>>(base, btot, bbuf, degi, beg, dinv, n);

    // 2. layer 1: MFMA transform -> gather (fused bias+self+relu, bf16 out)
    k_gemm1_mfma<<<(n + 127) / 128, 256, 0, stream>>>(x, W1s, hb, n);
    k_gather1<<<(n + 3) / 4, 256, 0, stream>>>(beg, degi, (const int*)bbuf, dinv,
                                               (const unsigned int*)hb, b1,
                                               (unsigned int*)h1b, n);

    // 3. layer 2: MFMA transform -> gather (fused bias+self)
    k_gemm2_mfma<<<(n + 63) / 64, 256, 0, stream>>>(h1b, W2s, h2b, n);
    k_gather2<<<(n + 3) / 4, 256, 0, stream>>>(beg, degi, (const int*)bbuf, dinv,
                                               (const unsigned short*)h2b, b2, out, n);
}

// Round 8
// 410.430 us; speedup vs baseline: 1.8324x; 1.0328x over previous
//
#include <hip/hip_runtime.h>
#include <hip/hip_bf16.h>

#define DIN 256
#define DHID 128
#define NCLS 47
#define BSHIFT 9                 // bucket = dst >> 9  (512 nodes/bucket)
#define BNODES 512
#define NPART 256                // edge partitions (one histogram each)
#define BCAPS 9216               // per-bucket LDS stage cap (lambda 8192 + 11 sigma)

typedef __attribute__((ext_vector_type(8))) short short8;   // 8 bf16 (4 VGPRs)
typedef __attribute__((ext_vector_type(4))) float f32x4;

__device__ __forceinline__ short f2bf(float f) {
    __bf16 b = (__bf16)f;                 // RNE convert
    return __builtin_bit_cast(short, b);
}
__device__ __forceinline__ float bfu(unsigned int u) {   // low 16 bits = bf16
    return __uint_as_float(u << 16);
}
__device__ __forceinline__ float bfh(unsigned int u) {   // high 16 bits = bf16
    return __uint_as_float(u & 0xffff0000u);
}

// ============ CSR build pass 1: per-partition bucket histograms ============
__global__ __launch_bounds__(256) void k_hist(const int* __restrict__ dst,
                                              int* __restrict__ ghist,
                                              int E, int NB, int chunk) {
    extern __shared__ int lh[];   // NB counters
    int blk = blockIdx.x, t = threadIdx.x;
    for (int i = t; i < NB; i += 256) lh[i] = 0;
    __syncthreads();
    int lo = blk * chunk, hi = min(E, lo + chunk);
    for (int i = lo + t; i < hi; i += 256)
        atomicAdd(&lh[dst[i] >> BSHIFT], 1);
    __syncthreads();
    for (int i = t; i < NB; i += 256) ghist[blk * NB + i] = lh[i];
}

// ============ CSR build pass 2: per-bucket column scan (parallel) ==========
// block b: goff[wg][b] = sum_{wg'<wg} ghist[wg'][b] (relative); btot[b] = total
__global__ __launch_bounds__(256) void k_colscan(const int* __restrict__ ghist,
                                                 int* __restrict__ goff,
                                                 int* __restrict__ btot, int NB) {
    __shared__ int wsum[4];
    int b = blockIdx.x, t = threadIdx.x;
    int v = ghist[t * NB + b];
    int incl = v;
    int lane = t & 63, w = t >> 6;
    #pragma unroll
    for (int off = 1; off < 64; off <<= 1) {
        int u = __shfl_up(incl, off, 64);
        if (lane >= off) incl += u;
    }
    if (lane == 63) wsum[w] = incl;
    __syncthreads();
    int wadd = 0;
    for (int i = 0; i < w; ++i) wadd += wsum[i];
    goff[t * NB + b] = wadd + incl - v;      // exclusive prefix (relative)
    if (t == 255) btot[b] = wadd + incl;     // column total
}

// 256-thread exclusive scan of btot -> lbase[0..255]; call with all threads
__device__ __forceinline__ void scan_btot(const int* __restrict__ btot, int NB,
                                          int* lbase, int* wsum) {
    int t = threadIdx.x;
    int v = (t < NB) ? btot[t] : 0;
    int incl = v;
    int lane = t & 63, w = t >> 6;
    #pragma unroll
    for (int off = 1; off < 64; off <<= 1) {
        int u = __shfl_up(incl, off, 64);
        if (lane >= off) incl += u;
    }
    if (lane == 63) wsum[w] = incl;
    __syncthreads();
    int wadd = 0;
    for (int i = 0; i < w; ++i) wadd += wsum[i];
    lbase[t] = wadd + incl - v;   // exclusive
    __syncthreads();
}

// ============ CSR build pass 3: scatter into bucket-grouped order ==========
// packed = src (17b) | (dst & 511) << 17 ; only LDS atomics
__global__ __launch_bounds__(256) void k_scatter(const int* __restrict__ src,
                                                 const int* __restrict__ dst,
                                                 const int* __restrict__ goff,
                                                 const int* __restrict__ btot,
                                                 unsigned int* __restrict__ bbuf,
                                                 int E, int NB, int chunk) {
    __shared__ int lcur[256];
    __shared__ int wsum[4];
    int blk = blockIdx.x, t = threadIdx.x;
    scan_btot(btot, NB, lcur, wsum);                   // lcur = base (exclusive scan)
    if (t < NB) lcur[t] += goff[blk * NB + t];
    __syncthreads();
    int lo = blk * chunk, hi = min(E, lo + chunk);
    for (int i = lo + t; i < hi; i += 256) {
        int d = dst[i];
        int b = d >> BSHIFT;
        int pos = atomicAdd(&lcur[b], 1);
        bbuf[pos] = (unsigned int)src[i] | ((unsigned int)(d & (BNODES - 1)) << 17);
    }
}

// ========== CSR build pass 4: per-bucket counting sort (in place) ==========
__global__ __launch_bounds__(256) void k_bsort(const int* __restrict__ btot,
                                               unsigned int* __restrict__ bbuf,
                                               int* __restrict__ degi,
                                               int* __restrict__ beg,
                                               float* __restrict__ dinv, int n, int NB) {
    __shared__ unsigned int stage[BCAPS];
    __shared__ int hist[BNODES];
    __shared__ int cur[BNODES];
    __shared__ int lbase[256];
    __shared__ int wsum[4];

    int b = blockIdx.x, t = threadIdx.x;
    scan_btot(btot, NB, lbase, wsum);
    int cnt = min(btot[b], BCAPS);
    int gbase = lbase[b];
    int node0 = b << BSHIFT;

    if (t < 128) { ((int2*)hist)[t] = (int2){0, 0}; ((int2*)hist)[t + 128] = (int2){0, 0}; }
    __syncthreads();

    for (int i = t; i < cnt; i += 256) {
        unsigned int p = bbuf[gbase + i];
        stage[i] = p;
        atomicAdd(&hist[p >> 17], 1);
    }
    __syncthreads();

    // exclusive scan of 512 counters: thread t owns pair (2t, 2t+1)
    int v0 = hist[2 * t], v1 = hist[2 * t + 1];
    int s = v0 + v1;
    int incl = s;
    int lane = t & 63, w = t >> 6;
    #pragma unroll
    for (int off = 1; off < 64; off <<= 1) {
        int u = __shfl_up(incl, off, 64);
        if (lane >= off) incl += u;
    }
    if (lane == 63) wsum[w] = incl;
    __syncthreads();
    int wadd = 0;
    for (int i = 0; i < w; ++i) wadd += wsum[i];
    int ex = wadd + incl - s;
    cur[2 * t] = ex;
    cur[2 * t + 1] = ex + v0;
    int nodeA = node0 + 2 * t, nodeB = node0 + 2 * t + 1;
    if (nodeA < n) {
        degi[nodeA] = v0;
        beg[nodeA]  = gbase + ex;
        dinv[nodeA] = rsqrtf((float)(v0 + 1));
    }
    if (nodeB < n) {
        degi[nodeB] = v1;
        beg[nodeB]  = gbase + ex + v0;
        dinv[nodeB] = rsqrtf((float)(v1 + 1));
    }
    __syncthreads();

    for (int i = t; i < cnt; i += 256) {
        unsigned int p = stage[i];
        int slot = atomicAdd(&cur[p >> 17], 1);
        bbuf[gbase + slot] = p & 0x1FFFFu;
    }
}

// ============ W1 & W2 -> bf16 B-fragment swizzles (one launch) =============
__global__ void k_prepW(const float* __restrict__ W1, const float* __restrict__ W2,
                        short* __restrict__ W1s, short* __restrict__ W2s) {
    int blk = blockIdx.x;
    if (blk < 16) {
        int tid = blk * 256 + threadIdx.x;   // 0..4095
        int frag = tid >> 6, lane = tid & 63;
        int kt = frag >> 3, nt = frag & 7;
        int quad = lane >> 4, col = lane & 15;
        #pragma unroll
        for (int j = 0; j < 8; ++j) {
            int k = kt * 32 + quad * 8 + j;
            W1s[(size_t)tid * 8 + j] = f2bf(W1[k * DHID + nt * 16 + col]);
        }
    } else {
        int tid = (blk - 16) * 256 + threadIdx.x;   // 0..1023
        int frag = tid >> 6, lane = tid & 63;
        int kt = frag >> 2, nt = frag & 3;
        int quad = lane >> 4, col = lane & 15;
        int c = nt * 16 + col;
        #pragma unroll
        for (int j = 0; j < 8; ++j) {
            int k = kt * 32 + quad * 8 + j;
            float v = (c < NCLS) ? W2[k * NCLS + c] : 0.0f;
            W2s[(size_t)tid * 8 + j] = f2bf(v);
        }
    }
}

// ===================== GEMM1 via MFMA: hb = bf16(x @ W1) ===================
__global__ __launch_bounds__(256) void k_gemm1_mfma(const float* __restrict__ x,
                                                    const short* __restrict__ W1s,
                                                    short* __restrict__ hb, int n) {
    __shared__ short lw[32768];  // 64 KB: full swizzled W1
    {
        const uint4* g = (const uint4*)W1s;
        uint4* l = (uint4*)lw;
        for (int i = threadIdx.x; i < 4096; i += 256) l[i] = g[i];
    }
    __syncthreads();

    int wave = threadIdx.x >> 6, lane = threadIdx.x & 63;
    int quad = lane >> 4, lrow = lane & 15;
    long long rowbase = (long long)blockIdx.x * 128 + wave * 32;

    f32x4 acc[2][8];
    #pragma unroll
    for (int rt = 0; rt < 2; ++rt)
        #pragma unroll
        for (int nt = 0; nt < 8; ++nt) acc[rt][nt] = (f32x4){0.f, 0.f, 0.f, 0.f};

    const short8* lf = (const short8*)lw;

    #pragma unroll
    for (int kt = 0; kt < 8; ++kt) {
        int k0 = kt * 32 + quad * 8;
        short8 a[2];
        #pragma unroll
        for (int rt = 0; rt < 2; ++rt) {
            long long row = rowbase + rt * 16 + lrow;
            float4 v0 = {0.f,0.f,0.f,0.f}, v1 = {0.f,0.f,0.f,0.f};
            if (row < n) {
                const float* xp = x + row * DIN + k0;
                v0 = *(const float4*)xp;
                v1 = *(const float4*)(xp + 4);
            }
            short8 av;
            av[0] = f2bf(v0.x); av[1] = f2bf(v0.y); av[2] = f2bf(v0.z); av[3] = f2bf(v0.w);
            av[4] = f2bf(v1.x); av[5] = f2bf(v1.y); av[6] = f2bf(v1.z); av[7] = f2bf(v1.w);
            a[rt] = av;
        }
        #pragma unroll
        for (int nt = 0; nt < 8; ++nt) {
            short8 b = lf[(kt * 8 + nt) * 64 + lane];
            acc[0][nt] = __builtin_amdgcn_mfma_f32_16x16x32_bf16(a[0], b, acc[0][nt], 0, 0, 0);
            acc[1][nt] = __builtin_amdgcn_mfma_f32_16x16x32_bf16(a[1], b, acc[1][nt], 0, 0, 0);
        }
    }
    #pragma unroll
    for (int rt = 0; rt < 2; ++rt)
        #pragma unroll
        for (int nt = 0; nt < 8; ++nt)
            #pragma unroll
            for (int r = 0; r < 4; ++r) {
                long long row = rowbase + rt * 16 + quad * 4 + r;
                if (row < n) hb[row * DHID + nt * 16 + lrow] = f2bf(acc[rt][nt][r]);
            }
}

// ===== gather layer 1 (bf16 h in, bf16 h1 out, 8x unroll, fused epilogue) ==
__global__ void k_gather1(const int* __restrict__ beg, const int* __restrict__ degi,
                          const int* __restrict__ ssrc, const float* __restrict__ dinv,
                          const unsigned int* __restrict__ hu, const float* __restrict__ b1,
                          unsigned int* __restrict__ h1u, int n) {
    int node = blockIdx.x * 4 + (threadIdx.x >> 6);
    int t = threadIdx.x & 63;
    if (node >= n) return;
    int cnt = degi[node];
    int bg  = beg[node];
    float ax = 0.f, ay = 0.f;
    int k = 0;
    for (; k + 8 <= cnt; k += 8) {
        int s[8]; float dv[8]; unsigned int u[8];
        #pragma unroll
        for (int j = 0; j < 8; ++j) s[j] = ssrc[bg + k + j];      // wave-uniform -> SGPR
        #pragma unroll
        for (int j = 0; j < 8; ++j) { dv[j] = dinv[s[j]]; u[j] = hu[(size_t)s[j] * 64 + t]; }
        #pragma unroll
        for (int j = 0; j < 8; ++j) { ax += dv[j] * bfu(u[j]); ay += dv[j] * bfh(u[j]); }
    }
    for (; k + 4 <= cnt; k += 4) {
        int s[4]; float dv[4]; unsigned int u[4];
        #pragma unroll
        for (int j = 0; j < 4; ++j) s[j] = ssrc[bg + k + j];
        #pragma unroll
        for (int j = 0; j < 4; ++j) { dv[j] = dinv[s[j]]; u[j] = hu[(size_t)s[j] * 64 + t]; }
        #pragma unroll
        for (int j = 0; j < 4; ++j) { ax += dv[j] * bfu(u[j]); ay += dv[j] * bfh(u[j]); }
    }
    for (; k < cnt; ++k) {
        int s = ssrc[bg + k];
        float ds = dinv[s];
        unsigned int u = hu[(size_t)s * 64 + t];
        ax += ds * bfu(u);
        ay += ds * bfh(u);
    }
    float di = dinv[node];
    unsigned int us = hu[(size_t)node * 64 + t];
    float2 bb = ((const float2*)b1)[t];
    float vx = di * ax + bfu(us) * di * di + bb.x;
    float vy = di * ay + bfh(us) * di * di + bb.y;
    vx = vx > 0.f ? vx : 0.f;
    vy = vy > 0.f ? vy : 0.f;
    unsigned int o = (unsigned int)(unsigned short)f2bf(vx)
                   | ((unsigned int)(unsigned short)f2bf(vy) << 16);
    h1u[(size_t)node * 64 + t] = o;
}

// ========== GEMM2 via MFMA: h2b[n,64] = bf16(h1b[n,128] @ W2pad) ===========
__global__ __launch_bounds__(256) void k_gemm2_mfma(const short* __restrict__ h1b,
                                                    const short* __restrict__ W2s,
                                                    short* __restrict__ h2b, int n) {
    __shared__ short lw[8192];  // 16 KB: swizzled padded W2
    {
        const uint4* g = (const uint4*)W2s;
        uint4* l = (uint4*)lw;
        for (int i = threadIdx.x; i < 1024; i += 256) l[i] = g[i];
    }
    __syncthreads();

    int wave = threadIdx.x >> 6, lane = threadIdx.x & 63;
    int quad = lane >> 4, lrow = lane & 15;
    long long row0 = (long long)blockIdx.x * 64 + wave * 16;

    f32x4 acc[4];
    #pragma unroll
    for (int nt = 0; nt < 4; ++nt) acc[nt] = (f32x4){0.f, 0.f, 0.f, 0.f};

    const short8* lf = (const short8*)lw;

    #pragma unroll
    for (int kt = 0; kt < 4; ++kt) {
        long long row = row0 + lrow;
        short8 a = (short8){0,0,0,0,0,0,0,0};
        if (row < n) a = *(const short8*)(h1b + row * DHID + kt * 32 + quad * 8);
        #pragma unroll
        for (int nt = 0; nt < 4; ++nt)
            acc[nt] = __builtin_amdgcn_mfma_f32_16x16x32_bf16(a, lf[(kt * 4 + nt) * 64 + lane], acc[nt], 0, 0, 0);
    }
    #pragma unroll
    for (int nt = 0; nt < 4; ++nt)
        #pragma unroll
        for (int r = 0; r < 4; ++r) {
            long long row = row0 + quad * 4 + r;
            if (row < n) h2b[row * 64 + nt * 16 + lrow] = f2bf(acc[nt][r]);
        }
}

// ===== gather layer 2 (bf16 padded h2, 8x unroll, fused epilogue) ==========
__global__ void k_gather2(const int* __restrict__ beg, const int* __restrict__ degi,
                          const int* __restrict__ ssrc, const float* __restrict__ dinv,
                          const unsigned short* __restrict__ h2b, const float* __restrict__ b2,
                          float* __restrict__ out, int n) {
    int node = blockIdx.x * 4 + (threadIdx.x >> 6);
    int t = threadIdx.x & 63;
    if (node >= n) return;
    int cnt = degi[node];
    int bg  = beg[node];
    float acc = 0.f;
    int k = 0;
    for (; k + 8 <= cnt; k += 8) {
        int s[8]; float dv[8]; unsigned int u[8];
        #pragma unroll
        for (int j = 0; j < 8; ++j) s[j] = ssrc[bg + k + j];
        #pragma unroll
        for (int j = 0; j < 8; ++j) { dv[j] = dinv[s[j]]; u[j] = h2b[(size_t)s[j] * 64 + t]; }
        #pragma unroll
        for (int j = 0; j < 8; ++j) acc += dv[j] * bfu(u[j]);
    }
    for (; k + 4 <= cnt; k += 4) {
        int s[4]; float dv[4]; unsigned int u[4];
        #pragma unroll
        for (int j = 0; j < 4; ++j) s[j] = ssrc[bg + k + j];
        #pragma unroll
        for (int j = 0; j < 4; ++j) { dv[j] = dinv[s[j]]; u[j] = h2b[(size_t)s[j] * 64 + t]; }
        #pragma unroll
        for (int j = 0; j < 4; ++j) acc += dv[j] * bfu(u[j]);
    }
    for (; k < cnt; ++k) {
        int s = ssrc[bg + k];
        acc += dinv[s] * bfu((unsigned int)h2b[(size_t)s * 64 + t]);
    }
    if (t < NCLS) {
        float di = dinv[node];
        float self = bfu((unsigned int)h2b[(size_t)node * 64 + t]);
        out[(size_t)node * NCLS + t] = di * acc + self * di * di + b2[t];
    }
}

// ===========================================================================
extern "C" void kernel_launch(void* const* d_in, const int* in_sizes, int n_in,
                              void* d_out, int out_size, void* d_ws, size_t ws_size,
                              hipStream_t stream) {
    const float* x  = (const float*)d_in[0];
    const int*   ei = (const int*)d_in[1];
    const float* W1 = (const float*)d_in[2];
    const float* b1 = (const float*)d_in[3];
    const float* W2 = (const float*)d_in[4];
    const float* b2 = (const float*)d_in[5];

    const int n = in_sizes[0] / DIN;   // 100000
    const int E = in_sizes[1] / 2;     // 1600000
    const int* src = ei;
    const int* dst = ei + E;
    float* out = (float*)d_out;

    const int NB = (n + BNODES - 1) >> BSHIFT;   // 196 buckets
    const int chunk = (E + NPART - 1) / NPART;   // 6250

    // workspace layout (~72 MB)
    char* w = (char*)d_ws;
    int*   ghist = (int*)w;                    w += (size_t)NPART * NB * 4;   // 200 KB
    int*   goff  = (int*)w;                    w += (size_t)NPART * NB * 4;   // 200 KB
    int*   btot  = (int*)w;                    w += ((size_t)NB * 4 + 15) & ~15ull;
    int*   degi  = (int*)w;                    w += (size_t)n * 4;
    int*   beg   = (int*)w;                    w += (size_t)n * 4;
    float* dinv  = (float*)w;                  w += (size_t)n * 4;
    short* W1s   = (short*)w;                  w += (size_t)32768 * 2;        // 64 KB
    short* W2s   = (short*)w;                  w += (size_t)8192 * 2;         // 16 KB
    unsigned int* bbuf = (unsigned int*)w;     w += (size_t)E * 4;            // 6.4 MB -> ssrc
    short* hb    = (short*)w;                  w += (size_t)n * DHID * 2;     // bf16 x@W1
    short* h1b   = (short*)w;                  w += (size_t)n * DHID * 2;     // bf16 relu layer1
    short* h2b   = (short*)w;                  w += (size_t)n * 64 * 2;       // bf16 h1@W2, N-pad 64

    // 1. CSR build (no global atomics, parallel scans) + weight swizzles
    k_prepW<<<20, 256, 0, stream>>>(W1, W2, W1s, W2s);
    k_hist<<<NPART, 256, NB * 4, stream>>>(dst, ghist, E, NB, chunk);
    k_colscan<<<NB, 256, 0, stream>>>(ghist, goff, btot, NB);
    k_scatter<<<NPART, 256, 0, stream>>>(src, dst, goff, btot, bbuf, E, NB, chunk);
    k_bsort<<<NB, 256, 0, stream>>>(btot, bbuf, degi, beg, dinv, n, NB);

    // 2. layer 1: MFMA transform -> gather (fused bias+self+relu, bf16 out)
    k_gemm1_mfma<<<(n + 127) / 128, 256, 0, stream>>>(x, W1s, hb, n);
    k_gather1<<<(n + 3) / 4, 256, 0, stream>>>(beg, degi, (const int*)bbuf, dinv,
                                               (const unsigned int*)hb, b1,
                                               (unsigned int*)h1b, n);

    // 3. layer 2: MFMA transform -> gather (fused bias+self)
    k_gemm2_mfma<<<(n + 63) / 64, 256, 0, stream>>>(h1b, W2s, h2b, n);
    k_gather2<<<(n + 3) / 4, 256, 0, stream>>>(beg, degi, (const int*)bbuf, dinv,
                                               (const unsigned short*)h2b, b2, out, n);
}

// Round 9
// 404.257 us; speedup vs baseline: 1.8603x; 1.0153x over previous
//
#include <hip/hip_runtime.h>
#include <hip/hip_bf16.h>

#define DIN 256
#define DHID 128
#define NCLS 47
#define BSHIFT 9                 // bucket = dst >> 9  (512 nodes/bucket)
#define BNODES 512
#define NPART 256                // edge partitions (one histogram each)
#define BCAPS 9216               // per-bucket LDS stage cap (lambda 8192 + 11 sigma)
#define CHUNKE 6400              // per-partition LDS stage cap (chunk = 6250)

typedef __attribute__((ext_vector_type(8))) short short8;   // 8 bf16 (4 VGPRs)
typedef __attribute__((ext_vector_type(4))) float f32x4;

__device__ __forceinline__ short f2bf(float f) {
    __bf16 b = (__bf16)f;                 // RNE convert
    return __builtin_bit_cast(short, b);
}
__device__ __forceinline__ float bfu(unsigned int u) {   // low 16 bits = bf16
    return __uint_as_float(u << 16);
}
__device__ __forceinline__ float bfh(unsigned int u) {   // high 16 bits = bf16
    return __uint_as_float(u & 0xffff0000u);
}

// ===== CSR pass 1 + weight swizzles fused (disjoint block ranges) ==========
__global__ __launch_bounds__(256) void k_prep_hist(const float* __restrict__ W1,
                                                   const float* __restrict__ W2,
                                                   short* __restrict__ W1s,
                                                   short* __restrict__ W2s,
                                                   const int* __restrict__ dst,
                                                   int* __restrict__ ghist,
                                                   int E, int NB, int chunk) {
    __shared__ int lh[256];
    int blk = blockIdx.x, t = threadIdx.x;
    if (blk < 16) {                      // W1 -> B-fragment swizzle
        int tid = blk * 256 + t;         // 0..4095
        int frag = tid >> 6, lane = tid & 63;
        int kt = frag >> 3, nt = frag & 7;
        int quad = lane >> 4, col = lane & 15;
        #pragma unroll
        for (int j = 0; j < 8; ++j) {
            int k = kt * 32 + quad * 8 + j;
            W1s[(size_t)tid * 8 + j] = f2bf(W1[k * DHID + nt * 16 + col]);
        }
    } else if (blk < 20) {               // W2 -> B-fragment swizzle (pad N to 64)
        int tid = (blk - 16) * 256 + t;  // 0..1023
        int frag = tid >> 6, lane = tid & 63;
        int kt = frag >> 2, nt = frag & 3;
        int quad = lane >> 4, col = lane & 15;
        int c = nt * 16 + col;
        #pragma unroll
        for (int j = 0; j < 8; ++j) {
            int k = kt * 32 + quad * 8 + j;
            float v = (c < NCLS) ? W2[k * NCLS + c] : 0.0f;
            W2s[(size_t)tid * 8 + j] = f2bf(v);
        }
    } else {                             // per-partition bucket histogram
        int p = blk - 20;
        for (int i = t; i < NB; i += 256) lh[i] = 0;
        __syncthreads();
        int lo = p * chunk, hi = min(E, lo + chunk);
        for (int i = lo + t; i < hi; i += 256)
            atomicAdd(&lh[dst[i] >> BSHIFT], 1);
        __syncthreads();
        for (int i = t; i < NB; i += 256) ghist[p * NB + i] = lh[i];
    }
}

// ============ CSR pass 2: per-bucket column scan (parallel) ================
__global__ __launch_bounds__(256) void k_colscan(const int* __restrict__ ghist,
                                                 int* __restrict__ goff,
                                                 int* __restrict__ btot, int NB) {
    __shared__ int wsum[4];
    int b = blockIdx.x, t = threadIdx.x;
    int v = ghist[t * NB + b];
    int incl = v;
    int lane = t & 63, w = t >> 6;
    #pragma unroll
    for (int off = 1; off < 64; off <<= 1) {
        int u = __shfl_up(incl, off, 64);
        if (lane >= off) incl += u;
    }
    if (lane == 63) wsum[w] = incl;
    __syncthreads();
    int wadd = 0;
    for (int i = 0; i < w; ++i) wadd += wsum[i];
    goff[t * NB + b] = wadd + incl - v;      // exclusive prefix (relative)
    if (t == 255) btot[b] = wadd + incl;     // column total
}

// 256-thread exclusive scan of btot -> lbase[0..255]; ends synced
__device__ __forceinline__ void scan_btot(const int* __restrict__ btot, int NB,
                                          int* lbase, int* wsum) {
    int t = threadIdx.x;
    int v = (t < NB) ? btot[t] : 0;
    int incl = v;
    int lane = t & 63, w = t >> 6;
    #pragma unroll
    for (int off = 1; off < 64; off <<= 1) {
        int u = __shfl_up(incl, off, 64);
        if (lane >= off) incl += u;
    }
    if (lane == 63) wsum[w] = incl;
    __syncthreads();
    int wadd = 0;
    for (int i = 0; i < w; ++i) wadd += wsum[i];
    lbase[t] = wadd + incl - v;   // exclusive
    __syncthreads();
}

// ===== CSR pass 3: scatter, LDS-staged so global writes are dest-ordered ===
// packed = src (17b) | (dst & 511) << 17 ; global writes coalesce per segment
__global__ __launch_bounds__(256) void k_scatter(const int* __restrict__ src,
                                                 const int* __restrict__ dst,
                                                 const int* __restrict__ ghist,
                                                 const int* __restrict__ goff,
                                                 const int* __restrict__ btot,
                                                 unsigned int* __restrict__ bbuf,
                                                 int E, int NB, int chunk) {
    __shared__ unsigned int stage[CHUNKE];   // 25.6 KB: chunk edges, bucket-sorted
    __shared__ int sdest[CHUNKE];            // 25.6 KB: absolute dest per slot
    __shared__ int lcur[256];
    __shared__ int gdst[256];
    __shared__ int wsum[4];

    int blk = blockIdx.x, t = threadIdx.x;

    scan_btot(btot, NB, gdst, wsum);         // gdst = global bucket base

    // local histogram (from ghist) scan -> lstart; fold into gdst and lcur
    int v = (t < NB) ? ghist[blk * NB + t] : 0;
    {
        int incl = v;
        int lane = t & 63, w = t >> 6;
        #pragma unroll
        for (int off = 1; off < 64; off <<= 1) {
            int u = __shfl_up(incl, off, 64);
            if (lane >= off) incl += u;
        }
        if (lane == 63) wsum[w] = incl;
        __syncthreads();
        int wadd = 0;
        for (int i = 0; i < w; ++i) wadd += wsum[i];
        int ex = wadd + incl - v;            // local exclusive prefix (lstart)
        lcur[t] = ex;
        if (t < NB) gdst[t] += goff[blk * NB + t] - ex;  // sdest = gdst[b] + slot
    }
    __syncthreads();

    int lo = blk * chunk, hi = min(E, lo + chunk), cnt = hi - lo;
    for (int i = lo + t; i < hi; i += 256) {
        int d = dst[i];
        int b = d >> BSHIFT;
        int slot = atomicAdd(&lcur[b], 1);
        stage[slot] = (unsigned int)src[i] | ((unsigned int)(d & (BNODES - 1)) << 17);
        sdest[slot] = gdst[b] + slot;
    }
    __syncthreads();
    for (int i = t; i < cnt; i += 256)       // consecutive i -> consecutive dest
        bbuf[sdest[i]] = stage[i];
}

// ========== CSR pass 4: per-bucket counting sort (in place) ================
__global__ __launch_bounds__(256) void k_bsort(const int* __restrict__ btot,
                                               unsigned int* __restrict__ bbuf,
                                               int* __restrict__ degi,
                                               int* __restrict__ beg,
                                               float* __restrict__ dinv, int n, int NB) {
    __shared__ unsigned int stage[BCAPS];
    __shared__ int hist[BNODES];
    __shared__ int cur[BNODES];
    __shared__ int lbase[256];
    __shared__ int wsum[4];

    int b = blockIdx.x, t = threadIdx.x;
    scan_btot(btot, NB, lbase, wsum);
    int cnt = min(btot[b], BCAPS);
    int gbase = lbase[b];
    int node0 = b << BSHIFT;

    if (t < 128) { ((int2*)hist)[t] = (int2){0, 0}; ((int2*)hist)[t + 128] = (int2){0, 0}; }
    __syncthreads();

    for (int i = t; i < cnt; i += 256) {
        unsigned int p = bbuf[gbase + i];
        stage[i] = p;
        atomicAdd(&hist[p >> 17], 1);
    }
    __syncthreads();

    // exclusive scan of 512 counters: thread t owns pair (2t, 2t+1)
    int v0 = hist[2 * t], v1 = hist[2 * t + 1];
    int s = v0 + v1;
    int incl = s;
    int lane = t & 63, w = t >> 6;
    #pragma unroll
    for (int off = 1; off < 64; off <<= 1) {
        int u = __shfl_up(incl, off, 64);
        if (lane >= off) incl += u;
    }
    if (lane == 63) wsum[w] = incl;
    __syncthreads();
    int wadd = 0;
    for (int i = 0; i < w; ++i) wadd += wsum[i];
    int ex = wadd + incl - s;
    cur[2 * t] = ex;
    cur[2 * t + 1] = ex + v0;
    int nodeA = node0 + 2 * t, nodeB = node0 + 2 * t + 1;
    if (nodeA < n) {
        degi[nodeA] = v0;
        beg[nodeA]  = gbase + ex;
        dinv[nodeA] = rsqrtf((float)(v0 + 1));
    }
    if (nodeB < n) {
        degi[nodeB] = v1;
        beg[nodeB]  = gbase + ex + v0;
        dinv[nodeB] = rsqrtf((float)(v1 + 1));
    }
    __syncthreads();

    for (int i = t; i < cnt; i += 256) {
        unsigned int p = stage[i];
        int slot = atomicAdd(&cur[p >> 17], 1);
        bbuf[gbase + slot] = p & 0x1FFFFu;
    }
}

// ===================== GEMM1 via MFMA: hb = bf16(x @ W1) ===================
__global__ __launch_bounds__(256) void k_gemm1_mfma(const float* __restrict__ x,
                                                    const short* __restrict__ W1s,
                                                    short* __restrict__ hb, int n) {
    __shared__ short lw[32768];  // 64 KB: full swizzled W1
    {
        const uint4* g = (const uint4*)W1s;
        uint4* l = (uint4*)lw;
        for (int i = threadIdx.x; i < 4096; i += 256) l[i] = g[i];
    }
    __syncthreads();

    int wave = threadIdx.x >> 6, lane = threadIdx.x & 63;
    int quad = lane >> 4, lrow = lane & 15;
    long long rowbase = (long long)blockIdx.x * 128 + wave * 32;

    f32x4 acc[2][8];
    #pragma unroll
    for (int rt = 0; rt < 2; ++rt)
        #pragma unroll
        for (int nt = 0; nt < 8; ++nt) acc[rt][nt] = (f32x4){0.f, 0.f, 0.f, 0.f};

    const short8* lf = (const short8*)lw;

    #pragma unroll
    for (int kt = 0; kt < 8; ++kt) {
        int k0 = kt * 32 + quad * 8;
        short8 a[2];
        #pragma unroll
        for (int rt = 0; rt < 2; ++rt) {
            long long row = rowbase + rt * 16 + lrow;
            float4 v0 = {0.f,0.f,0.f,0.f}, v1 = {0.f,0.f,0.f,0.f};
            if (row < n) {
                const float* xp = x + row * DIN + k0;
                v0 = *(const float4*)xp;
                v1 = *(const float4*)(xp + 4);
            }
            short8 av;
            av[0] = f2bf(v0.x); av[1] = f2bf(v0.y); av[2] = f2bf(v0.z); av[3] = f2bf(v0.w);
            av[4] = f2bf(v1.x); av[5] = f2bf(v1.y); av[6] = f2bf(v1.z); av[7] = f2bf(v1.w);
            a[rt] = av;
        }
        #pragma unroll
        for (int nt = 0; nt < 8; ++nt) {
            short8 b = lf[(kt * 8 + nt) * 64 + lane];
            acc[0][nt] = __builtin_amdgcn_mfma_f32_16x16x32_bf16(a[0], b, acc[0][nt], 0, 0, 0);
            acc[1][nt] = __builtin_amdgcn_mfma_f32_16x16x32_bf16(a[1], b, acc[1][nt], 0, 0, 0);
        }
    }
    #pragma unroll
    for (int rt = 0; rt < 2; ++rt)
        #pragma unroll
        for (int nt = 0; nt < 8; ++nt)
            #pragma unroll
            for (int r = 0; r < 4; ++r) {
                long long row = rowbase + rt * 16 + quad * 4 + r;
                if (row < n) hb[row * DHID + nt * 16 + lrow] = f2bf(acc[rt][nt][r]);
            }
}

// ===== gather layer 1 (bf16 h in, bf16 h1 out, 8x unroll, fused epilogue) ==
__global__ void k_gather1(const int* __restrict__ beg, const int* __restrict__ degi,
                          const int* __restrict__ ssrc, const float* __restrict__ dinv,
                          const unsigned int* __restrict__ hu, const float* __restrict__ b1,
                          unsigned int* __restrict__ h1u, int n) {
    int node = blockIdx.x * 4 + (threadIdx.x >> 6);
    int t = threadIdx.x & 63;
    if (node >= n) return;
    int cnt = degi[node];
    int bg  = beg[node];
    float ax = 0.f, ay = 0.f;
    int k = 0;
    for (; k + 8 <= cnt; k += 8) {
        int s[8]; float dv[8]; unsigned int u[8];
        #pragma unroll
        for (int j = 0; j < 8; ++j) s[j] = ssrc[bg + k + j];      // wave-uniform -> SGPR
        #pragma unroll
        for (int j = 0; j < 8; ++j) { dv[j] = dinv[s[j]]; u[j] = hu[(size_t)s[j] * 64 + t]; }
        #pragma unroll
        for (int j = 0; j < 8; ++j) { ax += dv[j] * bfu(u[j]); ay += dv[j] * bfh(u[j]); }
    }
    for (; k + 4 <= cnt; k += 4) {
        int s[4]; float dv[4]; unsigned int u[4];
        #pragma unroll
        for (int j = 0; j < 4; ++j) s[j] = ssrc[bg + k + j];
        #pragma unroll
        for (int j = 0; j < 4; ++j) { dv[j] = dinv[s[j]]; u[j] = hu[(size_t)s[j] * 64 + t]; }
        #pragma unroll
        for (int j = 0; j < 4; ++j) { ax += dv[j] * bfu(u[j]); ay += dv[j] * bfh(u[j]); }
    }
    for (; k < cnt; ++k) {
        int s = ssrc[bg + k];
        float ds = dinv[s];
        unsigned int u = hu[(size_t)s * 64 + t];
        ax += ds * bfu(u);
        ay += ds * bfh(u);
    }
    float di = dinv[node];
    unsigned int us = hu[(size_t)node * 64 + t];
    float2 bb = ((const float2*)b1)[t];
    float vx = di * ax + bfu(us) * di * di + bb.x;
    float vy = di * ay + bfh(us) * di * di + bb.y;
    vx = vx > 0.f ? vx : 0.f;
    vy = vy > 0.f ? vy : 0.f;
    unsigned int o = (unsigned int)(unsigned short)f2bf(vx)
                   | ((unsigned int)(unsigned short)f2bf(vy) << 16);
    h1u[(size_t)node * 64 + t] = o;
}

// ========== GEMM2 via MFMA: h2b[n,64] = bf16(h1b[n,128] @ W2pad) ===========
__global__ __launch_bounds__(256) void k_gemm2_mfma(const short* __restrict__ h1b,
                                                    const short* __restrict__ W2s,
                                                    short* __restrict__ h2b, int n) {
    __shared__ short lw[8192];  // 16 KB: swizzled padded W2
    {
        const uint4* g = (const uint4*)W2s;
        uint4* l = (uint4*)lw;
        for (int i = threadIdx.x; i < 1024; i += 256) l[i] = g[i];
    }
    __syncthreads();

    int wave = threadIdx.x >> 6, lane = threadIdx.x & 63;
    int quad = lane >> 4, lrow = lane & 15;
    long long row0 = (long long)blockIdx.x * 64 + wave * 16;

    f32x4 acc[4];
    #pragma unroll
    for (int nt = 0; nt < 4; ++nt) acc[nt] = (f32x4){0.f, 0.f, 0.f, 0.f};

    const short8* lf = (const short8*)lw;

    #pragma unroll
    for (int kt = 0; kt < 4; ++kt) {
        long long row = row0 + lrow;
        short8 a = (short8){0,0,0,0,0,0,0,0};
        if (row < n) a = *(const short8*)(h1b + row * DHID + kt * 32 + quad * 8);
        #pragma unroll
        for (int nt = 0; nt < 4; ++nt)
            acc[nt] = __builtin_amdgcn_mfma_f32_16x16x32_bf16(a, lf[(kt * 4 + nt) * 64 + lane], acc[nt], 0, 0, 0);
    }
    #pragma unroll
    for (int nt = 0; nt < 4; ++nt)
        #pragma unroll
        for (int r = 0; r < 4; ++r) {
            long long row = row0 + quad * 4 + r;
            if (row < n) h2b[row * 64 + nt * 16 + lrow] = f2bf(acc[nt][r]);
        }
}

// ===== gather layer 2 (bf16 padded h2, 8x unroll, fused epilogue) ==========
__global__ void k_gather2(const int* __restrict__ beg, const int* __restrict__ degi,
                          const int* __restrict__ ssrc, const float* __restrict__ dinv,
                          const unsigned short* __restrict__ h2b, const float* __restrict__ b2,
                          float* __restrict__ out, int n) {
    int node = blockIdx.x * 4 + (threadIdx.x >> 6);
    int t = threadIdx.x & 63;
    if (node >= n) return;
    int cnt = degi[node];
    int bg  = beg[node];
    float acc = 0.f;
    int k = 0;
    for (; k + 8 <= cnt; k += 8) {
        int s[8]; float dv[8]; unsigned int u[8];
        #pragma unroll
        for (int j = 0; j < 8; ++j) s[j] = ssrc[bg + k + j];
        #pragma unroll
        for (int j = 0; j < 8; ++j) { dv[j] = dinv[s[j]]; u[j] = h2b[(size_t)s[j] * 64 + t]; }
        #pragma unroll
        for (int j = 0; j < 8; ++j) acc += dv[j] * bfu(u[j]);
    }
    for (; k + 4 <= cnt; k += 4) {
        int s[4]; float dv[4]; unsigned int u[4];
        #pragma unroll
        for (int j = 0; j < 4; ++j) s[j] = ssrc[bg + k + j];
        #pragma unroll
        for (int j = 0; j < 4; ++j) { dv[j] = dinv[s[j]]; u[j] = h2b[(size_t)s[j] * 64 + t]; }
        #pragma unroll
        for (int j = 0; j < 4; ++j) acc += dv[j] * bfu(u[j]);
    }
    for (; k < cnt; ++k) {
        int s = ssrc[bg + k];
        acc += dinv[s] * bfu((unsigned int)h2b[(size_t)s * 64 + t]);
    }
    if (t < NCLS) {
        float di = dinv[node];
        float self = bfu((unsigned int)h2b[(size_t)node * 64 + t]);
        out[(size_t)node * NCLS + t] = di * acc + self * di * di + b2[t];
    }
}

// ===========================================================================
extern "C" void kernel_launch(void* const* d_in, const int* in_sizes, int n_in,
                              void* d_out, int out_size, void* d_ws, size_t ws_size,
                              hipStream_t stream) {
    const float* x  = (const float*)d_in[0];
    const int*   ei = (const int*)d_in[1];
    const float* W1 = (const float*)d_in[2];
    const float* b1 = (const float*)d_in[3];
    const float* W2 = (const float*)d_in[4];
    const float* b2 = (const float*)d_in[5];

    const int n = in_sizes[0] / DIN;   // 100000
    const int E = in_sizes[1] / 2;     // 1600000
    const int* src = ei;
    const int* dst = ei + E;
    float* out = (float*)d_out;

    const int NB = (n + BNODES - 1) >> BSHIFT;   // 196 buckets
    const int chunk = (E + NPART - 1) / NPART;   // 6250

    // workspace layout (~72 MB)
    char* w = (char*)d_ws;
    int*   ghist = (int*)w;                    w += (size_t)NPART * NB * 4;   // 200 KB
    int*   goff  = (int*)w;                    w += (size_t)NPART * NB * 4;   // 200 KB
    int*   btot  = (int*)w;                    w += ((size_t)NB * 4 + 15) & ~15ull;
    int*   degi  = (int*)w;                    w += (size_t)n * 4;
    int*   beg   = (int*)w;                    w += (size_t)n * 4;
    float* dinv  = (float*)w;                  w += (size_t)n * 4;
    short* W1s   = (short*)w;                  w += (size_t)32768 * 2;        // 64 KB
    short* W2s   = (short*)w;                  w += (size_t)8192 * 2;         // 16 KB
    unsigned int* bbuf = (unsigned int*)w;     w += (size_t)E * 4;            // 6.4 MB -> ssrc
    short* hb    = (short*)w;                  w += (size_t)n * DHID * 2;     // bf16 x@W1
    short* h1b   = (short*)w;                  w += (size_t)n * DHID * 2;     // bf16 relu layer1
    short* h2b   = (short*)w;                  w += (size_t)n * 64 * 2;       // bf16 h1@W2, N-pad 64

    // 1. CSR build (no global atomics, dest-ordered writes) + weight swizzle
    k_prep_hist<<<20 + NPART, 256, 0, stream>>>(W1, W2, W1s, W2s, dst, ghist, E, NB, chunk);
    k_colscan<<<NB, 256, 0, stream>>>(ghist, goff, btot, NB);
    k_scatter<<<NPART, 256, 0, stream>>>(src, dst, ghist, goff, btot, bbuf, E, NB, chunk);
    k_bsort<<<NB, 256, 0, stream>>>(btot, bbuf, degi, beg, dinv, n, NB);

    // 2. layer 1: MFMA transform -> gather (fused bias+self+relu, bf16 out)
    k_gemm1_mfma<<<(n + 127) / 128, 256, 0, stream>>>(x, W1s, hb, n);
    k_gather1<<<(n + 3) / 4, 256, 0, stream>>>(beg, degi, (const int*)bbuf, dinv,
                                               (const unsigned int*)hb, b1,
                                               (unsigned int*)h1b, n);

    // 3. layer 2: MFMA transform -> gather (fused bias+self)
    k_gemm2_mfma<<<(n + 63) / 64, 256, 0, stream>>>(h1b, W2s, h2b, n);
    k_gather2<<<(n + 3) / 4, 256, 0, stream>>>(beg, degi, (const int*)bbuf, dinv,
                                               (const unsigned short*)h2b, b2, out, n);
}